// Round 5
// baseline (365.981 us; speedup 1.0000x reference)
//
#include <hip/hip_runtime.h>
#include <math.h>

// dims
constexpr int Nn = 1024, Bb = 8, HIDc = 256, Hh = 8, DHc = 32;

typedef __bf16 bf16x8 __attribute__((ext_vector_type(8)));
typedef __bf16 bf16x4 __attribute__((ext_vector_type(4)));
typedef float  f32x4  __attribute__((ext_vector_type(4)));

// ---------------------------------------------------------------------------
// Weight convert+transpose: Wt[m][k] = bf16(W[k][m]) for all 9 weight mats.
// ---------------------------------------------------------------------------
struct WCvtArgs {
    const float* src[9];
    int K[9], M[9], dstOff[9], tiles[9];
};

__global__ __launch_bounds__(256)
void wcvt_k(WCvtArgs a, __bf16* __restrict__ Wt)
{
    __shared__ float ts[32][33];
    int bid = blockIdx.x, i = 0;
    while (bid >= a.tiles[i]) { bid -= a.tiles[i]; ++i; }
    const int K = a.K[i], M = a.M[i];
    const int tilesM = M >> 5;
    const int m0 = (bid % tilesM) << 5, k0 = (bid / tilesM) << 5;
    const float* src = a.src[i];
    __bf16* dst = Wt + a.dstOff[i];
    const int tx = threadIdx.x & 31, ty = threadIdx.x >> 5;
    #pragma unroll
    for (int j = 0; j < 4; ++j) {
        const int row = ty + 8 * j;
        ts[row][tx] = src[(size_t)(k0 + row) * M + m0 + tx];
    }
    __syncthreads();
    #pragma unroll
    for (int j = 0; j < 4; ++j) {
        const int row = ty + 8 * j;
        dst[(size_t)(m0 + row) * K + k0 + tx] = (__bf16)ts[tx][row];
    }
}

// ---------------------------------------------------------------------------
// Mask precompute: 1 byte per (b,q,c,col); bit(2t)= (d==1), bit(2t+1)= (d>=1)
// for key = c*64 + t*16 + col.
// ---------------------------------------------------------------------------
__global__ __launch_bounds__(256)
void mask_k(const int* __restrict__ dist, unsigned char* __restrict__ mbc)
{
    const int idx = blockIdx.x * 256 + threadIdx.x;   // 2M entries
    const int col = idx & 15, c = (idx >> 4) & 15, q = (idx >> 8) & 1023, b = idx >> 18;
    const int* dp = dist + ((((size_t)b << 10) + q) << 10) + c * 64 + col;
    unsigned int m = 0;
    #pragma unroll
    for (int t = 0; t < 4; ++t) {
        const int d = dp[t * 16];
        m |= ((d == 1 ? 1u : 0u) | (d >= 1 ? 2u : 0u)) << (2 * t);
    }
    mbc[idx] = (unsigned char)m;
}

// ---------------------------------------------------------------------------
// Input prep: xinb = bf16(nodes + sinusoidal PE).
// ---------------------------------------------------------------------------
__global__ __launch_bounds__(256)
void xin_k(const float* __restrict__ nodes, __bf16* __restrict__ xinb)
{
    const int idx = blockIdx.x * 256 + threadIdx.x;   // 1M threads
    const int token = idx >> 7, k2 = (idx & 127) * 2;
    const int n = token >> 3;
    const float e = (float)k2 * (1.0f / 256.0f);
    const float freq = exp2f(-13.287712379549449f * e);   // 10000^-e
    const float ang = (float)n * freq;
    const float2 nd = *(const float2*)(nodes + (size_t)token * 256 + k2);
    __bf16 o0 = (__bf16)(nd.x + sinf(ang));
    __bf16 o1 = (__bf16)(nd.y + cosf(ang));
    __bf16* p = xinb + (size_t)token * 256 + k2;
    p[0] = o0; p[1] = o1;
}

// ---------------------------------------------------------------------------
// MFMA dense with LDS weight staging.
// Block = 512 threads = 8 waves = 2 row-tiles x 4 col-quarters (64 cols each).
// EPI: 0 = LN(resid + y) -> fp32 + bf16   3 = LN(y) -> fp32 + bf16
//      1 = ReLU -> bf16 (M=512 via grid.y)
//      2 = QKV: grid.y = 0/1/2 -> q(scaled by log2e/sqrt(DH))/k/v^T(permuted)
// ---------------------------------------------------------------------------
template<int K, int EPI>
__global__ __launch_bounds__(512)
void dense_mfma(const __bf16* __restrict__ Xb, const __bf16* __restrict__ Wt,
                const float* __restrict__ bias, const float* __restrict__ resid,
                const float* __restrict__ gamma, const float* __restrict__ beta,
                float* __restrict__ outf, __bf16* __restrict__ outb,
                __bf16* __restrict__ outb2, __bf16* __restrict__ outb3)
{
    constexpr int KC = 64;           // k per staged chunk
    constexpr int NCH = K / KC;
    __shared__ __bf16 wlds[256][72];
    __shared__ float red[2][4][16][2];

    const int tid = threadIdx.x;
    const int lane = tid & 63;
    const int wv = tid >> 6;         // 0..7
    const int rt = wv >> 2;          // row-tile 0..1
    const int cq = wv & 3;           // col-quarter 0..3
    const int col = lane & 15;
    const int quad = lane >> 4;
    const int cg = blockIdx.y;

    int rowA, n0 = 0, b = 0;
    if constexpr (EPI == 2) {
        b = blockIdx.x & 7;
        n0 = (blockIdx.x >> 3) * 32 + rt * 16;
        rowA = (n0 + col) * 8 + b;
    } else {
        rowA = blockIdx.x * 32 + rt * 16 + col;
    }

    const __bf16* wsrc = Wt + (size_t)(cg * 256) * K;

    f32x4 acc[4];
    #pragma unroll
    for (int t = 0; t < 4; ++t) acc[t] = (f32x4){0.f, 0.f, 0.f, 0.f};

    for (int ck = 0; ck < NCH; ++ck) {
        // A-frags from global (independent of LDS)
        bf16x8 af[2];
        #pragma unroll
        for (int kc = 0; kc < 2; ++kc)
            af[kc] = *(const bf16x8*)(Xb + (size_t)rowA * K + ck * KC + kc * 32 + quad * 8);
        if (ck) __syncthreads();
        // cooperative stage: 256 rows x 64 k = 2048 bf16x8, 4/thread
        #pragma unroll
        for (int i = 0; i < 4; ++i) {
            const int v = i * 512 + tid;
            const int m = v >> 3, kv = v & 7;
            *(bf16x8*)&wlds[m][kv * 8] =
                *(const bf16x8*)(wsrc + (size_t)m * K + ck * KC + kv * 8);
        }
        __syncthreads();
        #pragma unroll
        for (int t = 0; t < 4; ++t) {
            #pragma unroll
            for (int kc = 0; kc < 2; ++kc) {
                const bf16x8 bfr = *(const bf16x8*)(&wlds[cq * 64 + t * 16 + col][kc * 32 + quad * 8]);
                acc[t] = __builtin_amdgcn_mfma_f32_16x16x32_bf16(af[kc], bfr, acc[t], 0, 0, 0);
            }
        }
    }

    if constexpr (EPI == 0 || EPI == 3) {
        float bb[4], gm[4], bt[4];
        #pragma unroll
        for (int t = 0; t < 4; ++t) {
            const int cc = cq * 64 + t * 16 + col;
            bb[t] = bias[cc]; gm[t] = gamma[cc]; bt[t] = beta[cc];
        }
        const int rbase = blockIdx.x * 32 + rt * 16 + quad * 4;
        float val[4][4];
        #pragma unroll
        for (int r = 0; r < 4; ++r) {
            float s1 = 0.f, s2 = 0.f;
            #pragma unroll
            for (int t = 0; t < 4; ++t) {
                float v = acc[t][r] + bb[t];
                if constexpr (EPI == 0)
                    v += resid[(size_t)(rbase + r) * 256 + cq * 64 + t * 16 + col];
                val[r][t] = v; s1 += v; s2 += v * v;
            }
            s1 += __shfl_xor(s1, 1); s1 += __shfl_xor(s1, 2);
            s1 += __shfl_xor(s1, 4); s1 += __shfl_xor(s1, 8);
            s2 += __shfl_xor(s2, 1); s2 += __shfl_xor(s2, 2);
            s2 += __shfl_xor(s2, 4); s2 += __shfl_xor(s2, 8);
            if (col == 0) {
                red[rt][cq][quad * 4 + r][0] = s1;
                red[rt][cq][quad * 4 + r][1] = s2;
            }
        }
        __syncthreads();
        #pragma unroll
        for (int r = 0; r < 4; ++r) {
            const int qr = quad * 4 + r;
            const float s1 = red[rt][0][qr][0] + red[rt][1][qr][0] + red[rt][2][qr][0] + red[rt][3][qr][0];
            const float s2 = red[rt][0][qr][1] + red[rt][1][qr][1] + red[rt][2][qr][1] + red[rt][3][qr][1];
            const float mu = s1 * (1.0f / 256.0f);
            const float rv = rsqrtf(s2 * (1.0f / 256.0f) - mu * mu + 1e-5f);
            const int row = rbase + r;
            #pragma unroll
            for (int t = 0; t < 4; ++t) {
                const float o = (val[r][t] - mu) * rv * gm[t] + bt[t];
                outf[(size_t)row * 256 + cq * 64 + t * 16 + col] = o;
                outb[(size_t)row * 256 + cq * 64 + t * 16 + col] = (__bf16)o;
            }
        }
    } else if constexpr (EPI == 1) {
        #pragma unroll
        for (int t = 0; t < 4; ++t) {
            const int cc = cg * 256 + cq * 64 + t * 16 + col;
            const float bbv = bias[cc];
            #pragma unroll
            for (int r = 0; r < 4; ++r) {
                const int row = blockIdx.x * 32 + rt * 16 + quad * 4 + r;
                outb[(size_t)row * 512 + cc] = (__bf16)fmaxf(acc[t][r] + bbv, 0.f);
            }
        }
    } else {  // EPI == 2, QKV.  q scaled by log2(e)/sqrt(DH) for exp2 softmax.
        const float qs = (cg == 0) ? 0.25505402616305625f : 1.0f;
        #pragma unroll
        for (int t = 0; t < 4; ++t) {
            const int cc = cq * 64 + t * 16 + col;
            const int h = cc >> 5, dh = cc & 31;
            const float bbv = bias[cg * 256 + cc];
            #pragma unroll
            for (int r = 0; r < 4; ++r) {
                const int n = n0 + quad * 4 + r;
                const __bf16 v = (__bf16)((acc[t][r] + bbv) * qs);
                if (cg == 0)
                    outb[(((size_t)(b * Hh + h)) * Nn + n) * DHc + dh] = v;
                else if (cg == 1)
                    outb2[(((size_t)(b * Hh + h)) * Nn + n) * DHc + dh] = v;
                else {
                    // v^T with columns permuted: pos(key) = (key&15)*4 + (key>>4)
                    const int nl = n & 63, c = n >> 6;
                    const int pos = (nl & 15) * 4 + (nl >> 4);
                    outb3[(((size_t)(b * Hh + h)) * DHc + dh) * Nn + c * 64 + pos] = v;
                }
            }
        }
    }
}

// ---------------------------------------------------------------------------
// MFMA flash attention, no-max softmax (scores provably tiny), L via MFMA
// ones-column, contiguous b64 P writes (V columns permuted to match).
// Block = one (b,h) x 64 queries (4 waves x 16 q). No barriers.
// ---------------------------------------------------------------------------
__global__ __launch_bounds__(256)
void attn_mfma(const __bf16* __restrict__ Qb, const __bf16* __restrict__ Kb,
               const __bf16* __restrict__ Vb, const unsigned char* __restrict__ MBc,
               __bf16* __restrict__ O)
{
    __shared__ __bf16 pbuf[4][16][72];
    const int tid = threadIdx.x;
    const int lane = tid & 63;
    const int wv = tid >> 6;
    const int col = lane & 15;
    const int quad = lane >> 4;
    const int bh = blockIdx.y;
    const int b = bh >> 3, h = bh & 7;
    const int q0 = blockIdx.x * 64 + wv * 16;
    const int hsel = (h < 2) ? 0 : 1;   // bit offset within 2-bit code
    const bool masked = (h < 6);

    const bf16x8 qf = *(const bf16x8*)(Qb + ((size_t)bh * Nn + q0 + col) * DHc + quad * 8);

    // ones B-fragment: column 0 of the extra tile accumulates row sums L
    bf16x8 onesf;
    {
        const __bf16 one = (__bf16)1.0f, zero = (__bf16)0.0f;
        #pragma unroll
        for (int j = 0; j < 8; ++j) onesf[j] = (col == 0) ? one : zero;
    }

    f32x4 O0 = {0.f, 0.f, 0.f, 0.f}, O1 = {0.f, 0.f, 0.f, 0.f}, O2 = {0.f, 0.f, 0.f, 0.f};

    const unsigned char* mbase = MBc + ((size_t)b << 18) + col;
    __bf16* pw = &pbuf[wv][0][0];
    const __bf16* prd = &pbuf[wv][col][0];
    const f32x4 zf = {0.f, 0.f, 0.f, 0.f};

    for (int c = 0; c < 16; ++c) {
        // --- QK^T: 4 tiles of 16 keys ---
        const __bf16* kp = Kb + ((size_t)bh * Nn + c * 64 + col) * DHc + quad * 8;
        f32x4 S[4];
        #pragma unroll
        for (int t = 0; t < 4; ++t) {
            const bf16x8 kf = *(const bf16x8*)(kp + (size_t)t * 16 * DHc);
            S[t] = __builtin_amdgcn_mfma_f32_16x16x32_bf16(qf, kf, zf, 0, 0, 0);
        }
        // --- mask (global heads skip) ---
        if (masked) {
            #pragma unroll
            for (int r = 0; r < 4; ++r) {
                const int q = q0 + quad * 4 + r;
                const unsigned int m = mbase[((size_t)q << 8) + (c << 4)];
                #pragma unroll
                for (int t = 0; t < 4; ++t)
                    if (!((m >> (2 * t + hsel)) & 1u)) S[t][r] = -INFINITY;
            }
        }
        // --- p = exp2(s) (q pre-scaled by log2e/sqrt(DH)); write P b64 ---
        #pragma unroll
        for (int r = 0; r < 4; ++r) {
            bf16x4 p4;
            #pragma unroll
            for (int t = 0; t < 4; ++t)
                p4[t] = (__bf16)__builtin_amdgcn_exp2f(S[t][r]);
            *(bf16x4*)(pw + (quad * 4 + r) * 72 + col * 4) = p4;
        }
        // --- PV + L: A = P[q][i], B = V^T[dh][i] (columns permuted) ---
        const __bf16* vp = Vb + ((size_t)bh * DHc) * Nn + c * 64 + quad * 8;
        #pragma unroll
        for (int kh = 0; kh < 2; ++kh) {
            const bf16x8 pf = *(const bf16x8*)(prd + kh * 32 + quad * 8);
            const bf16x8 v0 = *(const bf16x8*)(vp + (size_t)col * Nn + kh * 32);
            const bf16x8 v1 = *(const bf16x8*)(vp + (size_t)(col + 16) * Nn + kh * 32);
            O0 = __builtin_amdgcn_mfma_f32_16x16x32_bf16(pf, v0, O0, 0, 0, 0);
            O1 = __builtin_amdgcn_mfma_f32_16x16x32_bf16(pf, v1, O1, 0, 0, 0);
            O2 = __builtin_amdgcn_mfma_f32_16x16x32_bf16(pf, onesf, O2, 0, 0, 0);
        }
    }
    // --- normalize (L in lanes col==0 of O2) + write (N,B,HID) bf16 ---
    #pragma unroll
    for (int r = 0; r < 4; ++r) {
        const float Lr = __shfl(O2[r], lane & 48);
        const float inv = 1.0f / Lr;
        const int q = q0 + quad * 4 + r;
        __bf16* op = O + ((size_t)q * Bb + b) * HIDc + h * DHc + col;
        op[0]  = (__bf16)(O0[r] * inv);
        op[16] = (__bf16)(O1[r] * inv);
    }
}

// ---------------------------------------------------------------------------
// Final: y = x[0] (tokens 0..7), batch-norm over B, scale/shift.
// ---------------------------------------------------------------------------
__global__ __launch_bounds__(256)
void final_bn(const float* __restrict__ x, const float* __restrict__ g,
              const float* __restrict__ bta, float* __restrict__ out)
{
    const int d = threadIdx.x;
    float y[8]; float mu = 0.0f;
    #pragma unroll
    for (int i = 0; i < 8; ++i) { y[i] = x[i * 256 + d]; mu += y[i]; }
    mu *= 0.125f;
    float var = 0.0f;
    #pragma unroll
    for (int i = 0; i < 8; ++i) { const float dd = y[i] - mu; var += dd * dd; }
    var *= 0.125f;
    const float r = rsqrtf(var + 1e-5f);
    const float gg = g[d], bb = bta[d];
    #pragma unroll
    for (int i = 0; i < 8; ++i) out[i * 256 + d] = (y[i] - mu) * r * gg + bb;
}

extern "C" void kernel_launch(void* const* d_in, const int* in_sizes, int n_in,
                              void* d_out, int out_size, void* d_ws, size_t ws_size,
                              hipStream_t stream)
{
    const float* nodes   = (const float*)d_in[0];
    const int*   dist    = (const int*)  d_in[1];
    const float* W_in    = (const float*)d_in[2];
    const float* b_in    = (const float*)d_in[3];
    const float* ln_in_g = (const float*)d_in[4];
    const float* ln_in_b = (const float*)d_in[5];
    const float* Wqkv    = (const float*)d_in[6];
    const float* bqkv    = (const float*)d_in[7];
    const float* Wo      = (const float*)d_in[8];
    const float* bo      = (const float*)d_in[9];
    const float* ln1_g   = (const float*)d_in[10];
    const float* ln1_b   = (const float*)d_in[11];
    const float* W1      = (const float*)d_in[12];
    const float* b1      = (const float*)d_in[13];
    const float* W2      = (const float*)d_in[14];
    const float* b2      = (const float*)d_in[15];
    const float* ln2_g   = (const float*)d_in[16];
    const float* ln2_b   = (const float*)d_in[17];
    const float* bn_g    = (const float*)d_in[18];
    const float* bn_b    = (const float*)d_in[19];

    // workspace (byte offsets), ~32.25 MB used
    char* ws = (char*)d_ws;
    float*  x    = (float*)(ws);                       // 8 MB fp32 residual
    __bf16* xb   = (__bf16*)(ws + 8388608);            // 4 MB bf16 activations
    unsigned char* mb = (unsigned char*)(ws + 12582912); // 2 MB packed mask
    __bf16* wt   = (__bf16*)(ws + 14680064);           // 2.25 MB bf16 weights^T
    __bf16* qb   = (__bf16*)(ws + 17039360);           // 4 MB
    __bf16* kb   = (__bf16*)(ws + 21233664);           // 4 MB
    __bf16* vb   = (__bf16*)(ws + 25427968);           // 4 MB
    __bf16* ob   = (__bf16*)(ws + 29622272);           // 4 MB
    __bf16* h1b  = qb;       // 8 MB, aliases qb+kb (dead during FFN)
    __bf16* xinb = qb;       // 4 MB, aliases qb (dead before qkv l0)

    WCvtArgs wa;
    wa.src[0] = W_in;           wa.K[0] = 256; wa.M[0] = 256; wa.dstOff[0] = 0;
    wa.src[1] = Wqkv;           wa.K[1] = 256; wa.M[1] = 768; wa.dstOff[1] = 65536;
    wa.src[2] = Wqkv + 196608;  wa.K[2] = 256; wa.M[2] = 768; wa.dstOff[2] = 262144;
    wa.src[3] = Wo;             wa.K[3] = 256; wa.M[3] = 256; wa.dstOff[3] = 458752;
    wa.src[4] = Wo + 65536;     wa.K[4] = 256; wa.M[4] = 256; wa.dstOff[4] = 524288;
    wa.src[5] = W1;             wa.K[5] = 256; wa.M[5] = 512; wa.dstOff[5] = 589824;
    wa.src[6] = W1 + 131072;    wa.K[6] = 256; wa.M[6] = 512; wa.dstOff[6] = 720896;
    wa.src[7] = W2;             wa.K[7] = 512; wa.M[7] = 256; wa.dstOff[7] = 851968;
    wa.src[8] = W2 + 131072;    wa.K[8] = 512; wa.M[8] = 256; wa.dstOff[8] = 983040;
    int total_tiles = 0;
    for (int i = 0; i < 9; ++i) { wa.tiles[i] = (wa.K[i] >> 5) * (wa.M[i] >> 5); total_tiles += wa.tiles[i]; }

    wcvt_k<<<total_tiles, 256, 0, stream>>>(wa, wt);
    mask_k<<<8192, 256, 0, stream>>>(dist, mb);
    xin_k<<<4096, 256, 0, stream>>>(nodes, xinb);

    // x, xb = LN(xin @ W_in + b_in)
    dense_mfma<256, 3><<<dim3(256, 1), 512, 0, stream>>>(
        xinb, wt + 0, b_in, nullptr, ln_in_g, ln_in_b, x, xb, nullptr, nullptr);

    for (int l = 0; l < 2; ++l) {
        __bf16* wqkv_t = wt + (l == 0 ? 65536 : 262144);
        __bf16* wo_t   = wt + (l == 0 ? 458752 : 524288);
        __bf16* w1_t   = wt + (l == 0 ? 589824 : 720896);
        __bf16* w2_t   = wt + (l == 0 ? 851968 : 983040);

        // q (scaled), k, v^T (cols permuted) bf16
        dense_mfma<256, 2><<<dim3(256, 3), 512, 0, stream>>>(
            xb, wqkv_t, bqkv + l * 768, nullptr, nullptr, nullptr,
            nullptr, qb, kb, vb);
        // attention -> ob bf16 (N,B,HID)
        attn_mfma<<<dim3(16, 64), 256, 0, stream>>>(qb, kb, vb, mb, ob);
        // x, xb = LN(x + ob @ Wo + bo)
        dense_mfma<256, 0><<<dim3(256, 1), 512, 0, stream>>>(
            ob, wo_t, bo + l * 256, x, ln1_g + l * 256, ln1_b + l * 256,
            x, xb, nullptr, nullptr);
        // h1b = relu(xb @ W1 + b1)  (bf16, M=512)
        dense_mfma<256, 1><<<dim3(256, 2), 512, 0, stream>>>(
            xb, w1_t, b1 + l * 512, nullptr, nullptr, nullptr,
            nullptr, h1b, nullptr, nullptr);
        // x, xb = LN(x + h1b @ W2 + b2)  (K=512)
        dense_mfma<512, 0><<<dim3(256, 1), 512, 0, stream>>>(
            h1b, w2_t, b2 + l * 256, x, ln2_g + l * 256, ln2_b + l * 256,
            x, xb, nullptr, nullptr);
    }

    final_bn<<<1, 256, 0, stream>>>(x, bn_g, bn_b, (float*)d_out);
}

// Round 6
// 307.032 us; speedup vs baseline: 1.1920x; 1.1920x over previous
//
#include <hip/hip_runtime.h>
#include <math.h>

// dims
constexpr int Nn = 1024, Bb = 8, HIDc = 256, Hh = 8, DHc = 32;

typedef __bf16 bf16x8 __attribute__((ext_vector_type(8)));
typedef __bf16 bf16x4 __attribute__((ext_vector_type(4)));
typedef float  f32x4  __attribute__((ext_vector_type(4)));

// ---------------------------------------------------------------------------
// prep_k: fused one-time preprocessing.
//   range A [0,1088): weight convert+transpose Wt[m][k] = bf16(W[k][m])
//   range B [1088,3136): mask pack  mp[b][q][c][quad][t] byte,
//          bit(2r+sel): sel0 = (d==1), sel1 = (d>=1), key = c*64+t*16+quad*4+r
//   range C [3136,7232): xinb = bf16(nodes + sinusoidal PE)
// ---------------------------------------------------------------------------
struct WCvtArgs {
    const float* src[9];
    int K[9], M[9], dstOff[9], tiles[9];
};

__global__ __launch_bounds__(256)
void prep_k(WCvtArgs a, __bf16* __restrict__ Wt,
            const int* __restrict__ dist, unsigned char* __restrict__ mp,
            const float* __restrict__ nodes, __bf16* __restrict__ xinb)
{
    __shared__ float ts[32][33];
    const int tid = threadIdx.x;
    if (blockIdx.x < 1088) {
        int bid = blockIdx.x, i = 0;
        while (bid >= a.tiles[i]) { bid -= a.tiles[i]; ++i; }
        const int K = a.K[i], M = a.M[i];
        const int tilesM = M >> 5;
        const int m0 = (bid % tilesM) << 5, k0 = (bid / tilesM) << 5;
        const float* src = a.src[i];
        __bf16* dst = Wt + a.dstOff[i];
        const int tx = tid & 31, ty = tid >> 5;
        #pragma unroll
        for (int j = 0; j < 4; ++j)
            ts[ty + 8 * j][tx] = src[(size_t)(k0 + ty + 8 * j) * M + m0 + tx];
        __syncthreads();
        #pragma unroll
        for (int j = 0; j < 4; ++j)
            dst[(size_t)(m0 + ty + 8 * j) * K + k0 + tx] = (__bf16)ts[tx][ty + 8 * j];
    } else if (blockIdx.x < 3136) {
        const int idx = (blockIdx.x - 1088) * 256 + tid;   // 524288 items
        const int quad = idx & 3, c = (idx >> 2) & 15, q = (idx >> 6) & 1023, b = idx >> 16;
        const int* dp = dist + ((((size_t)b << 10) + q) << 10) + c * 64 + quad * 4;
        uchar4 out;
        unsigned char* po = &out.x;
        #pragma unroll
        for (int t = 0; t < 4; ++t) {
            const int4 v = *(const int4*)(dp + t * 16);
            unsigned int code = 0;
            const int dd[4] = {v.x, v.y, v.z, v.w};
            #pragma unroll
            for (int r = 0; r < 4; ++r)
                code |= ((dd[r] == 1 ? 1u : 0u) | (dd[r] >= 1 ? 2u : 0u)) << (2 * r);
            po[t] = (unsigned char)code;
        }
        *(uchar4*)(mp + ((((size_t)b << 10) + q) << 8) + (c << 4) + (quad << 2)) = out;
    } else {
        const int idx = (blockIdx.x - 3136) * 256 + tid;   // 1M items
        const int token = idx >> 7, k2 = (idx & 127) * 2;
        const int n = token >> 3;
        const float e = (float)k2 * (1.0f / 256.0f);
        const float freq = exp2f(-13.287712379549449f * e);
        const float ang = (float)n * freq;
        const float2 nd = *(const float2*)(nodes + (size_t)token * 256 + k2);
        __bf16* p = xinb + (size_t)token * 256 + k2;
        p[0] = (__bf16)(nd.x + sinf(ang));
        p[1] = (__bf16)(nd.y + cosf(ang));
    }
}

// ---------------------------------------------------------------------------
// MFMA dense, software-pipelined LDS weight staging.
// Block = 256 thr = 4 waves = 2 row-tiles x 2 col-halves; tile 32 rows x 256 cols.
// All A-frags loaded upfront; W chunk k+1 prefetched to regs during chunk k MFMAs.
// EPI: 0 = LN(resid+y) -> fp32+bf16   3 = LN(y) -> fp32+bf16
//      1 = ReLU -> bf16 (M=512 via grid.y)
//      2 = QKV -> q(scaled log2e/sqrt(DH)) / k / v, all (B,H,N,DH) bf16
// ---------------------------------------------------------------------------
template<int K, int EPI>
__global__ __launch_bounds__(256)
void dense_mfma(const __bf16* __restrict__ Xb, const __bf16* __restrict__ Wt,
                const float* __restrict__ bias, const float* __restrict__ resid,
                const float* __restrict__ gamma, const float* __restrict__ beta,
                float* __restrict__ outf, __bf16* __restrict__ outb,
                __bf16* __restrict__ outb2, __bf16* __restrict__ outb3)
{
    constexpr int NCH = K / 64;
    __shared__ __bf16 wlds[256][72];
    __shared__ float red[2][2][16][2];

    const int tid = threadIdx.x;
    const int lane = tid & 63;
    const int wv = tid >> 6;
    const int rt = wv >> 1;          // row-tile 0..1
    const int ch = wv & 1;           // col-half 0..1
    const int col = lane & 15;
    const int quad = lane >> 4;
    const int cg = blockIdx.y;
    const int rowA = blockIdx.x * 32 + rt * 16 + col;

    const __bf16* wsrc = Wt + (size_t)(cg * 256) * K;
    const int mrow = tid >> 3;            // 0..31
    const int kcol = (tid & 7) * 8;       // 0..56

    // all A-fragments upfront (independent loads)
    bf16x8 af[NCH][2];
    #pragma unroll
    for (int ck = 0; ck < NCH; ++ck)
        #pragma unroll
        for (int kc = 0; kc < 2; ++kc)
            af[ck][kc] = *(const bf16x8*)(Xb + (size_t)rowA * K + ck * 64 + kc * 32 + quad * 8);

    // prefetch W chunk 0
    bf16x8 wreg[8];
    #pragma unroll
    for (int i = 0; i < 8; ++i)
        wreg[i] = *(const bf16x8*)(wsrc + (size_t)(i * 32 + mrow) * K + kcol);

    f32x4 acc[8];
    #pragma unroll
    for (int t = 0; t < 8; ++t) acc[t] = (f32x4){0.f, 0.f, 0.f, 0.f};

    for (int ck = 0; ck < NCH; ++ck) {
        if (ck) __syncthreads();
        #pragma unroll
        for (int i = 0; i < 8; ++i)
            *(bf16x8*)&wlds[i * 32 + mrow][kcol] = wreg[i];
        if (ck + 1 < NCH) {
            #pragma unroll
            for (int i = 0; i < 8; ++i)
                wreg[i] = *(const bf16x8*)(wsrc + (size_t)(i * 32 + mrow) * K + (ck + 1) * 64 + kcol);
        }
        __syncthreads();
        #pragma unroll
        for (int t = 0; t < 8; ++t)
            #pragma unroll
            for (int kc = 0; kc < 2; ++kc) {
                const bf16x8 bfr = *(const bf16x8*)(&wlds[ch * 128 + t * 16 + col][kc * 32 + quad * 8]);
                acc[t] = __builtin_amdgcn_mfma_f32_16x16x32_bf16(af[ck][kc], bfr, acc[t], 0, 0, 0);
            }
    }

    if constexpr (EPI == 0 || EPI == 3) {
        float bb[8], gm[8], bt[8];
        #pragma unroll
        for (int t = 0; t < 8; ++t) {
            const int cc = ch * 128 + t * 16 + col;
            bb[t] = bias[cc]; gm[t] = gamma[cc]; bt[t] = beta[cc];
        }
        const int rbase = blockIdx.x * 32 + rt * 16 + quad * 4;
        float val[4][8];
        #pragma unroll
        for (int r = 0; r < 4; ++r) {
            float s1 = 0.f, s2 = 0.f;
            #pragma unroll
            for (int t = 0; t < 8; ++t) {
                float v = acc[t][r] + bb[t];
                if constexpr (EPI == 0)
                    v += resid[(size_t)(rbase + r) * 256 + ch * 128 + t * 16 + col];
                val[r][t] = v; s1 += v; s2 += v * v;
            }
            s1 += __shfl_xor(s1, 1); s1 += __shfl_xor(s1, 2);
            s1 += __shfl_xor(s1, 4); s1 += __shfl_xor(s1, 8);
            s2 += __shfl_xor(s2, 1); s2 += __shfl_xor(s2, 2);
            s2 += __shfl_xor(s2, 4); s2 += __shfl_xor(s2, 8);
            if (col == 0) {
                red[rt][ch][quad * 4 + r][0] = s1;
                red[rt][ch][quad * 4 + r][1] = s2;
            }
        }
        __syncthreads();
        #pragma unroll
        for (int r = 0; r < 4; ++r) {
            const int qr = quad * 4 + r;
            const float s1 = red[rt][0][qr][0] + red[rt][1][qr][0];
            const float s2 = red[rt][0][qr][1] + red[rt][1][qr][1];
            const float mu = s1 * (1.0f / 256.0f);
            const float rv = rsqrtf(s2 * (1.0f / 256.0f) - mu * mu + 1e-5f);
            const int row = rbase + r;
            #pragma unroll
            for (int t = 0; t < 8; ++t) {
                const float o = (val[r][t] - mu) * rv * gm[t] + bt[t];
                outf[(size_t)row * 256 + ch * 128 + t * 16 + col] = o;
                outb[(size_t)row * 256 + ch * 128 + t * 16 + col] = (__bf16)o;
            }
        }
    } else if constexpr (EPI == 1) {
        #pragma unroll
        for (int t = 0; t < 8; ++t) {
            const int cc = cg * 256 + ch * 128 + t * 16 + col;
            const float bbv = bias[cc];
            #pragma unroll
            for (int r = 0; r < 4; ++r) {
                const int row = blockIdx.x * 32 + rt * 16 + quad * 4 + r;
                outb[(size_t)row * 512 + cc] = (__bf16)fmaxf(acc[t][r] + bbv, 0.f);
            }
        }
    } else {  // EPI == 2, QKV: natural (B,H,N,DH) for q,k,v; q scaled
        const float qs = (cg == 0) ? 0.25505402616305625f : 1.0f;  // log2e/sqrt(32)
        #pragma unroll
        for (int t = 0; t < 8; ++t) {
            const int cc = ch * 128 + t * 16 + col;
            const int h = cc >> 5, dh = cc & 31;
            const float bbv = bias[cg * 256 + cc];
            #pragma unroll
            for (int r = 0; r < 4; ++r) {
                const int token = blockIdx.x * 32 + rt * 16 + quad * 4 + r;
                const int n = token >> 3, b = token & 7;
                const __bf16 v = (__bf16)((acc[t][r] + bbv) * qs);
                __bf16* dst = (cg == 0) ? outb : (cg == 1) ? outb2 : outb3;
                dst[(((size_t)(b * Hh + h)) * Nn + n) * DHc + dh] = v;
            }
        }
    }
}

// ---------------------------------------------------------------------------
// vt_k: V (B,H,N,DH) -> V^T (B,H,DH,N), 32x32 LDS tile transpose.
// ---------------------------------------------------------------------------
__global__ __launch_bounds__(256)
void vt_k(const __bf16* __restrict__ V, __bf16* __restrict__ VT)
{
    __shared__ __bf16 ts[32][33];
    const int bh = blockIdx.x >> 5;
    const int n0 = (blockIdx.x & 31) * 32;
    const __bf16* src = V + ((size_t)bh * Nn + n0) * DHc;
    __bf16* dst = VT + (size_t)bh * DHc * Nn + n0;
    const int tx = threadIdx.x & 31, ty = threadIdx.x >> 5;
    #pragma unroll
    for (int j = 0; j < 4; ++j)
        ts[ty + 8 * j][tx] = src[(size_t)(ty + 8 * j) * DHc + tx];
    __syncthreads();
    #pragma unroll
    for (int j = 0; j < 4; ++j)
        dst[(size_t)(ty + 8 * j) * Nn + tx] = ts[tx][ty + 8 * j];
}

// ---------------------------------------------------------------------------
// MFMA flash attention, swapped-operand QK (S^T in C-layout -> natural-key
// P writes), no-max exp2 softmax, L via ones-column MFMA, 2 q-tiles/wave.
// Block = 4 waves x 32 q = 128 q; grid (8, B*H). No barriers.
// ---------------------------------------------------------------------------
__global__ __launch_bounds__(256)
void attn_mfma(const __bf16* __restrict__ Qb, const __bf16* __restrict__ Kb,
               const __bf16* __restrict__ Vt, const unsigned char* __restrict__ MP,
               __bf16* __restrict__ O)
{
    __shared__ __bf16 pbuf[4][2][16][72];
    const int tid = threadIdx.x;
    const int lane = tid & 63;
    const int wv = tid >> 6;
    const int col = lane & 15;
    const int quad = lane >> 4;
    const int bh = blockIdx.y;
    const int b = bh >> 3, h = bh & 7;
    const int qbase = blockIdx.x * 128 + wv * 32;
    const int hsel = (h < 2) ? 0 : 1;
    const bool masked = (h < 6);

    // Q as B-operand: lane(col=q, quad) holds Q[q][dh=quad*8..]
    bf16x8 qf[2];
    #pragma unroll
    for (int j = 0; j < 2; ++j)
        qf[j] = *(const bf16x8*)(Qb + ((size_t)bh * Nn + qbase + j * 16 + col) * DHc + quad * 8);

    bf16x8 onesf;
    {
        const __bf16 one = (__bf16)1.0f, zero = (__bf16)0.0f;
        #pragma unroll
        for (int j = 0; j < 8; ++j) onesf[j] = (col == 0) ? one : zero;
    }

    f32x4 O0[2], O1[2], OL[2];
    #pragma unroll
    for (int j = 0; j < 2; ++j) {
        O0[j] = (f32x4){0.f, 0.f, 0.f, 0.f};
        O1[j] = (f32x4){0.f, 0.f, 0.f, 0.f};
        OL[j] = (f32x4){0.f, 0.f, 0.f, 0.f};
    }
    const f32x4 zf = {0.f, 0.f, 0.f, 0.f};

    for (int c = 0; c < 16; ++c) {
        // K as A-operand: lane(col=key, quad) holds K[key][dh=quad*8..]
        bf16x8 kf[4];
        #pragma unroll
        for (int t = 0; t < 4; ++t)
            kf[t] = *(const bf16x8*)(Kb + ((size_t)bh * Nn + c * 64 + t * 16 + col) * DHc + quad * 8);

        #pragma unroll
        for (int j = 0; j < 2; ++j) {
            // S^T tiles: D[key=quad*4+r (+t*16)][q=col]
            f32x4 S[4];
            #pragma unroll
            for (int t = 0; t < 4; ++t)
                S[t] = __builtin_amdgcn_mfma_f32_16x16x32_bf16(kf[t], qf[j], zf, 0, 0, 0);
            if (masked) {
                const int q = qbase + j * 16 + col;
                const uchar4 mk = *(const uchar4*)(MP + ((((size_t)b << 10) + q) << 8) + (c << 4) + (quad << 2));
                const unsigned char mb[4] = {mk.x, mk.y, mk.z, mk.w};
                #pragma unroll
                for (int t = 0; t < 4; ++t)
                    #pragma unroll
                    for (int r = 0; r < 4; ++r)
                        if (!((mb[t] >> (2 * r + hsel)) & 1)) S[t][r] = -INFINITY;
            }
            // p = exp2(s); write 4 consecutive keys per b64 (natural order)
            #pragma unroll
            for (int t = 0; t < 4; ++t) {
                bf16x4 p4;
                #pragma unroll
                for (int r = 0; r < 4; ++r)
                    p4[r] = (__bf16)__builtin_amdgcn_exp2f(S[t][r]);
                *(bf16x4*)(&pbuf[wv][j][col][t * 16 + quad * 4]) = p4;
            }
        }
        // PV: A = P[q][key] (row col), B = V^T rows (natural key order)
        const __bf16* vp = Vt + (size_t)bh * DHc * Nn + c * 64 + quad * 8;
        #pragma unroll
        for (int kh = 0; kh < 2; ++kh) {
            const bf16x8 v0 = *(const bf16x8*)(vp + (size_t)col * Nn + kh * 32);
            const bf16x8 v1 = *(const bf16x8*)(vp + (size_t)(col + 16) * Nn + kh * 32);
            #pragma unroll
            for (int j = 0; j < 2; ++j) {
                const bf16x8 pf = *(const bf16x8*)(&pbuf[wv][j][col][kh * 32 + quad * 8]);
                O0[j] = __builtin_amdgcn_mfma_f32_16x16x32_bf16(pf, v0, O0[j], 0, 0, 0);
                O1[j] = __builtin_amdgcn_mfma_f32_16x16x32_bf16(pf, v1, O1[j], 0, 0, 0);
                OL[j] = __builtin_amdgcn_mfma_f32_16x16x32_bf16(pf, onesf, OL[j], 0, 0, 0);
            }
        }
    }
    // normalize (L in col==0 lanes of OL) + write (N,B,HID) bf16
    #pragma unroll
    for (int j = 0; j < 2; ++j)
        #pragma unroll
        for (int r = 0; r < 4; ++r) {
            const float Lr = __shfl(OL[j][r], lane & 48);
            const float inv = 1.0f / Lr;
            const int q = qbase + j * 16 + quad * 4 + r;
            __bf16* op = O + ((size_t)q * Bb + b) * HIDc + h * DHc + col;
            op[0]  = (__bf16)(O0[j][r] * inv);
            op[16] = (__bf16)(O1[j][r] * inv);
        }
}

// ---------------------------------------------------------------------------
// Final: y = x[0] (tokens 0..7), batch-norm over B, scale/shift.
// ---------------------------------------------------------------------------
__global__ __launch_bounds__(256)
void final_bn(const float* __restrict__ x, const float* __restrict__ g,
              const float* __restrict__ bta, float* __restrict__ out)
{
    const int d = threadIdx.x;
    float y[8]; float mu = 0.0f;
    #pragma unroll
    for (int i = 0; i < 8; ++i) { y[i] = x[i * 256 + d]; mu += y[i]; }
    mu *= 0.125f;
    float var = 0.0f;
    #pragma unroll
    for (int i = 0; i < 8; ++i) { const float dd = y[i] - mu; var += dd * dd; }
    var *= 0.125f;
    const float r = rsqrtf(var + 1e-5f);
    const float gg = g[d], bb = bta[d];
    #pragma unroll
    for (int i = 0; i < 8; ++i) out[i * 256 + d] = (y[i] - mu) * r * gg + bb;
}

extern "C" void kernel_launch(void* const* d_in, const int* in_sizes, int n_in,
                              void* d_out, int out_size, void* d_ws, size_t ws_size,
                              hipStream_t stream)
{
    const float* nodes   = (const float*)d_in[0];
    const int*   dist    = (const int*)  d_in[1];
    const float* W_in    = (const float*)d_in[2];
    const float* b_in    = (const float*)d_in[3];
    const float* ln_in_g = (const float*)d_in[4];
    const float* ln_in_b = (const float*)d_in[5];
    const float* Wqkv    = (const float*)d_in[6];
    const float* bqkv    = (const float*)d_in[7];
    const float* Wo      = (const float*)d_in[8];
    const float* bo      = (const float*)d_in[9];
    const float* ln1_g   = (const float*)d_in[10];
    const float* ln1_b   = (const float*)d_in[11];
    const float* W1      = (const float*)d_in[12];
    const float* b1      = (const float*)d_in[13];
    const float* W2      = (const float*)d_in[14];
    const float* b2      = (const float*)d_in[15];
    const float* ln2_g   = (const float*)d_in[16];
    const float* ln2_b   = (const float*)d_in[17];
    const float* bn_g    = (const float*)d_in[18];
    const float* bn_b    = (const float*)d_in[19];

    // workspace (byte offsets), 32.25 MB used
    char* ws = (char*)d_ws;
    float*  x    = (float*)(ws);                         // 8 MB fp32 residual
    __bf16* xb   = (__bf16*)(ws + 8388608);              // 4 MB bf16 activations
    unsigned char* mp = (unsigned char*)(ws + 12582912); // 2 MB packed mask
    __bf16* wt   = (__bf16*)(ws + 14680064);             // 2.25 MB weights^T
    __bf16* qb   = (__bf16*)(ws + 17039360);             // 4 MB
    __bf16* kb   = (__bf16*)(ws + 21233664);             // 4 MB
    __bf16* vb   = (__bf16*)(ws + 25427968);             // 4 MB (V natural)
    __bf16* vtb  = (__bf16*)(ws + 29622272);             // 4 MB (V^T)
    __bf16* ob   = vb;       // attn output aliases vb (dead after vt_k)
    __bf16* h1b  = qb;       // 8 MB, aliases qb+kb (dead during FFN)
    __bf16* xinb = qb;       // 4 MB, aliases qb (dead before qkv l0)

    WCvtArgs wa;
    wa.src[0] = W_in;           wa.K[0] = 256; wa.M[0] = 256; wa.dstOff[0] = 0;
    wa.src[1] = Wqkv;           wa.K[1] = 256; wa.M[1] = 768; wa.dstOff[1] = 65536;
    wa.src[2] = Wqkv + 196608;  wa.K[2] = 256; wa.M[2] = 768; wa.dstOff[2] = 262144;
    wa.src[3] = Wo;             wa.K[3] = 256; wa.M[3] = 256; wa.dstOff[3] = 458752;
    wa.src[4] = Wo + 65536;     wa.K[4] = 256; wa.M[4] = 256; wa.dstOff[4] = 524288;
    wa.src[5] = W1;             wa.K[5] = 256; wa.M[5] = 512; wa.dstOff[5] = 589824;
    wa.src[6] = W1 + 131072;    wa.K[6] = 256; wa.M[6] = 512; wa.dstOff[6] = 720896;
    wa.src[7] = W2;             wa.K[7] = 512; wa.M[7] = 256; wa.dstOff[7] = 851968;
    wa.src[8] = W2 + 131072;    wa.K[8] = 512; wa.M[8] = 256; wa.dstOff[8] = 983040;
    for (int i = 0; i < 9; ++i) wa.tiles[i] = (wa.K[i] >> 5) * (wa.M[i] >> 5);
    // total wcvt tiles = 1088; mask blocks = 2048; xin blocks = 4096

    prep_k<<<7232, 256, 0, stream>>>(wa, wt, dist, mp, nodes, xinb);

    // x, xb = LN(xin @ W_in + b_in)
    dense_mfma<256, 3><<<dim3(256, 1), 256, 0, stream>>>(
        xinb, wt + 0, b_in, nullptr, ln_in_g, ln_in_b, x, xb, nullptr, nullptr);

    for (int l = 0; l < 2; ++l) {
        __bf16* wqkv_t = wt + (l == 0 ? 65536 : 262144);
        __bf16* wo_t   = wt + (l == 0 ? 458752 : 524288);
        __bf16* w1_t   = wt + (l == 0 ? 589824 : 720896);
        __bf16* w2_t   = wt + (l == 0 ? 851968 : 983040);

        // q (scaled), k, v natural bf16
        dense_mfma<256, 2><<<dim3(256, 3), 256, 0, stream>>>(
            xb, wqkv_t, bqkv + l * 768, nullptr, nullptr, nullptr,
            nullptr, qb, kb, vb);
        // V -> V^T
        vt_k<<<2048, 256, 0, stream>>>(vb, vtb);
        // attention -> ob bf16 (N,B,HID)
        attn_mfma<<<dim3(8, 64), 256, 0, stream>>>(qb, kb, vtb, mp, ob);
        // x, xb = LN(x + ob @ Wo + bo)
        dense_mfma<256, 0><<<dim3(256, 1), 256, 0, stream>>>(
            ob, wo_t, bo + l * 256, x, ln1_g + l * 256, ln1_b + l * 256,
            x, xb, nullptr, nullptr);
        // h1b = relu(xb @ W1 + b1)  (bf16, M=512)
        dense_mfma<256, 1><<<dim3(256, 2), 256, 0, stream>>>(
            xb, w1_t, b1 + l * 512, nullptr, nullptr, nullptr,
            nullptr, h1b, nullptr, nullptr);
        // x, xb = LN(x + h1b @ W2 + b2)  (K=512)
        dense_mfma<512, 0><<<dim3(256, 1), 256, 0, stream>>>(
            h1b, w2_t, b2 + l * 256, x, ln2_g + l * 256, ln2_b + l * 256,
            x, xb, nullptr, nullptr);
    }

    final_bn<<<1, 256, 0, stream>>>(x, bn_g, bn_b, (float*)d_out);
}

// Round 7
// 263.045 us; speedup vs baseline: 1.3913x; 1.1672x over previous
//
#include <hip/hip_runtime.h>
#include <math.h>

// dims
constexpr int Nn = 1024, Bb = 8, HIDc = 256, Hh = 8, DHc = 32;

typedef __bf16 bf16x8 __attribute__((ext_vector_type(8)));
typedef __bf16 bf16x4 __attribute__((ext_vector_type(4)));
typedef float  f32x4  __attribute__((ext_vector_type(4)));

// ---------------------------------------------------------------------------
// prep_k: fused one-time preprocessing.
//   [0,1088):     weight convert+transpose Wt[m][k] = bf16(W[k][m])
//   [1088,3136):  mask pack  mp[b][n][c*16 + quad*4 + t], bit(2r+sel):
//                 sel0=(d==1), sel1=(d>=1), key = c*64 + t*16 + quad*4 + r
//   [3136,7232):  xinb[(b*1024+n)*256+k] = bf16(nodes[n][b][k] + PE(n,k))
// ---------------------------------------------------------------------------
struct WCvtArgs {
    const float* src[9];
    int K[9], M[9], dstOff[9], tiles[9];
};

__global__ __launch_bounds__(256)
void prep_k(WCvtArgs a, __bf16* __restrict__ Wt,
            const int* __restrict__ dist, unsigned char* __restrict__ mp,
            const float* __restrict__ nodes, __bf16* __restrict__ xinb)
{
    __shared__ float ts[32][33];
    const int tid = threadIdx.x;
    if (blockIdx.x < 1088) {
        int bid = blockIdx.x, i = 0;
        while (bid >= a.tiles[i]) { bid -= a.tiles[i]; ++i; }
        const int K = a.K[i], M = a.M[i];
        const int tilesM = M >> 5;
        const int m0 = (bid % tilesM) << 5, k0 = (bid / tilesM) << 5;
        const float* src = a.src[i];
        __bf16* dst = Wt + a.dstOff[i];
        const int tx = tid & 31, ty = tid >> 5;
        #pragma unroll
        for (int j = 0; j < 4; ++j)
            ts[ty + 8 * j][tx] = src[(size_t)(k0 + ty + 8 * j) * M + m0 + tx];
        __syncthreads();
        #pragma unroll
        for (int j = 0; j < 4; ++j)
            dst[(size_t)(m0 + ty + 8 * j) * K + k0 + tx] = (__bf16)ts[tx][ty + 8 * j];
    } else if (blockIdx.x < 3136) {
        const int idx = (blockIdx.x - 1088) * 256 + tid;   // 524288 items
        const int quad = idx & 3, c = (idx >> 2) & 15, q = (idx >> 6) & 1023, b = idx >> 16;
        const int* dp = dist + ((((size_t)b << 10) + q) << 10) + c * 64 + quad * 4;
        uchar4 out;
        unsigned char* po = &out.x;
        #pragma unroll
        for (int t = 0; t < 4; ++t) {
            const int4 v = *(const int4*)(dp + t * 16);
            unsigned int code = 0;
            const int dd[4] = {v.x, v.y, v.z, v.w};
            #pragma unroll
            for (int r = 0; r < 4; ++r)
                code |= ((dd[r] == 1 ? 1u : 0u) | (dd[r] >= 1 ? 2u : 0u)) << (2 * r);
            po[t] = (unsigned char)code;
        }
        *(uchar4*)(mp + ((((size_t)b << 10) + q) << 8) + (c << 4) + (quad << 2)) = out;
    } else {
        const int idx = (blockIdx.x - 3136) * 256 + tid;   // 1M items
        const int token = idx >> 7, k2 = (idx & 127) * 2;  // token = b*1024 + n
        const int b = token >> 10, n = token & 1023;
        const float e = (float)k2 * (1.0f / 256.0f);
        const float freq = exp2f(-13.287712379549449f * e);
        const float ang = (float)n * freq;
        const float2 nd = *(const float2*)(nodes + ((size_t)(n * 8 + b)) * 256 + k2);
        __bf16* p = xinb + (size_t)token * 256 + k2;
        p[0] = (__bf16)(nd.x + sinf(ang));
        p[1] = (__bf16)(nd.y + cosf(ang));
    }
}

// ---------------------------------------------------------------------------
// gemm8: one 256-col GEMM stage. Block = 4 waves = 2 row-tiles x 2 col-halves.
// Weights staged per 64-k chunk into wlds with register prefetch pipeline.
// af: K/32 bf16x8 A-fragments (rows block-local). acc: 8 f32x4 tiles.
// ---------------------------------------------------------------------------
template<int NCH>
__device__ __forceinline__ void gemm8(const bf16x8* af, const __bf16* __restrict__ wsrc,
                                      __bf16 (*wlds)[72], int mrow, int kcol,
                                      int ch, int col, int quad, f32x4* acc)
{
    constexpr int K = NCH * 64;
    bf16x8 wreg[8];
    #pragma unroll
    for (int i = 0; i < 8; ++i)
        wreg[i] = *(const bf16x8*)(wsrc + (size_t)(i * 32 + mrow) * K + kcol);
    #pragma unroll
    for (int t = 0; t < 8; ++t) acc[t] = (f32x4){0.f, 0.f, 0.f, 0.f};
    for (int ck = 0; ck < NCH; ++ck) {
        __syncthreads();
        #pragma unroll
        for (int i = 0; i < 8; ++i)
            *(bf16x8*)&wlds[i * 32 + mrow][kcol] = wreg[i];
        if (ck + 1 < NCH) {
            #pragma unroll
            for (int i = 0; i < 8; ++i)
                wreg[i] = *(const bf16x8*)(wsrc + (size_t)(i * 32 + mrow) * K + (ck + 1) * 64 + kcol);
        }
        __syncthreads();
        #pragma unroll
        for (int t = 0; t < 8; ++t)
            #pragma unroll
            for (int kc = 0; kc < 2; ++kc) {
                const bf16x8 bfr = *(const bf16x8*)(&wlds[ch * 128 + t * 16 + col][kc * 32 + quad * 8]);
                acc[t] = __builtin_amdgcn_mfma_f32_16x16x32_bf16(af[ck * 2 + kc], bfr, acc[t], 0, 0, 0);
            }
    }
}

// ---------------------------------------------------------------------------
// layer_k: fused transformer block slab (32 token-rows per block, 256 blocks).
//   stage A: y = Ain @ w0 + b0 (+ xres if RESID) -> LN(g1,be1)
//   if FFN:  h1 = relu(xA @ w1 + b1);  y2 = h1 @ w2 + b2 + xA -> LN(g2,be2)
//   final LN output -> xout fp32 (full, or n==0 rows only if LASTX)
//   if QKV:  q(scaled log2e/sqrt(DH)) / k -> (B,H,N,DH); v -> V^T (B,H,DH,N)
// Token layout is (B,N,HID): token = b*1024 + n.
// ---------------------------------------------------------------------------
template<bool RESID, bool FFN, bool QKV, bool LASTX>
__global__ __launch_bounds__(256)
void layer_k(const __bf16* __restrict__ Ain, const float* __restrict__ xres,
             const __bf16* __restrict__ w0, const float* __restrict__ b0,
             const float* __restrict__ g1, const float* __restrict__ be1,
             const __bf16* __restrict__ w1, const float* __restrict__ b1_,
             const __bf16* __restrict__ w2, const float* __restrict__ b2_,
             const float* __restrict__ g2, const float* __restrict__ be2,
             const __bf16* __restrict__ wq, const float* __restrict__ bq,
             float* __restrict__ xout,
             __bf16* __restrict__ qb, __bf16* __restrict__ kb, __bf16* __restrict__ vtb)
{
    __shared__ char smem[36864];                    // wlds / trans union
    __bf16 (*wlds)[72]  = (__bf16 (*)[72])smem;     // [256][72] weight staging
    __bf16 (*trans)[520] = (__bf16 (*)[520])smem;   // [32][520] act transpose
    __shared__ float red[2][2][16][2];

    const int tid = threadIdx.x;
    const int lane = tid & 63;
    const int wv = tid >> 6;
    const int rt = wv >> 1, ch = wv & 1;
    const int col = lane & 15, quad = lane >> 4;
    const int row0 = blockIdx.x * 32;
    const int rowL = rt * 16 + col;                 // local A-row for this lane
    const int mrow = tid >> 3, kcol = (tid & 7) * 8;
    const int trow = rt * 16 + quad * 4;            // local C-row base

    // ---- stage A ----
    bf16x8 afA[8];
    #pragma unroll
    for (int kc = 0; kc < 8; ++kc)
        afA[kc] = *(const bf16x8*)(Ain + (size_t)(row0 + rowL) * 256 + kc * 32 + quad * 8);
    f32x4 acc[8];
    gemm8<4>(afA, w0, wlds, mrow, kcol, ch, col, quad, acc);

    float val[4][8];
    {
        float bb[8], gm[8], bt[8];
        #pragma unroll
        for (int t = 0; t < 8; ++t) {
            const int cc = ch * 128 + t * 16 + col;
            bb[t] = b0[cc]; gm[t] = g1[cc]; bt[t] = be1[cc];
        }
        #pragma unroll
        for (int r = 0; r < 4; ++r) {
            float s1 = 0.f, s2 = 0.f;
            #pragma unroll
            for (int t = 0; t < 8; ++t) {
                float v = acc[t][r] + bb[t];
                if (RESID) v += xres[(size_t)(row0 + trow + r) * 256 + ch * 128 + t * 16 + col];
                val[r][t] = v; s1 += v; s2 += v * v;
            }
            s1 += __shfl_xor(s1, 1); s1 += __shfl_xor(s1, 2);
            s1 += __shfl_xor(s1, 4); s1 += __shfl_xor(s1, 8);
            s2 += __shfl_xor(s2, 1); s2 += __shfl_xor(s2, 2);
            s2 += __shfl_xor(s2, 4); s2 += __shfl_xor(s2, 8);
            if (col == 0) { red[rt][ch][quad * 4 + r][0] = s1; red[rt][ch][quad * 4 + r][1] = s2; }
        }
        __syncthreads();
        #pragma unroll
        for (int r = 0; r < 4; ++r) {
            const int qr = quad * 4 + r;
            const float s1 = red[rt][0][qr][0] + red[rt][1][qr][0];
            const float s2 = red[rt][0][qr][1] + red[rt][1][qr][1];
            const float mu = s1 * (1.0f / 256.0f);
            const float rv = rsqrtf(s2 * (1.0f / 256.0f) - mu * mu + 1e-5f);
            #pragma unroll
            for (int t = 0; t < 8; ++t) {
                const float o = (val[r][t] - mu) * rv * gm[t] + bt[t];
                val[r][t] = o;
                trans[trow + r][ch * 128 + t * 16 + col] = (__bf16)o;
                if (!FFN)   // fused1: this LN is the kernel's final LN
                    xout[(size_t)(row0 + trow + r) * 256 + ch * 128 + t * 16 + col] = o;
            }
        }
        __syncthreads();
    }

    if (FFN) {
        // ---- FFN: h1 = relu(xA @ W1 + b1), 2 m-halves of 256 ----
        bf16x8 af1[8];
        #pragma unroll
        for (int kc = 0; kc < 8; ++kc)
            af1[kc] = *(const bf16x8*)(&trans[rowL][kc * 32 + quad * 8]);
        bf16x4 h1p[2][8];
        #pragma unroll
        for (int mh = 0; mh < 2; ++mh) {
            f32x4 accb[8];
            gemm8<4>(af1, w1 + (size_t)mh * 256 * 256, wlds, mrow, kcol, ch, col, quad, accb);
            #pragma unroll
            for (int t = 0; t < 8; ++t) {
                const float bbv = b1_[mh * 256 + ch * 128 + t * 16 + col];
                #pragma unroll
                for (int r = 0; r < 4; ++r)
                    h1p[mh][t][r] = (__bf16)fmaxf(accb[t][r] + bbv, 0.f);
            }
        }
        __syncthreads();
        #pragma unroll
        for (int mh = 0; mh < 2; ++mh)
            #pragma unroll
            for (int t = 0; t < 8; ++t)
                #pragma unroll
                for (int r = 0; r < 4; ++r)
                    trans[trow + r][mh * 256 + ch * 128 + t * 16 + col] = h1p[mh][t][r];
        __syncthreads();

        // ---- y2 = h1 @ W2 + b2 + xA -> LN2 ----
        bf16x8 af2[16];
        #pragma unroll
        for (int kc = 0; kc < 16; ++kc)
            af2[kc] = *(const bf16x8*)(&trans[rowL][kc * 32 + quad * 8]);
        f32x4 accc[8];
        gemm8<8>(af2, w2, wlds, mrow, kcol, ch, col, quad, accc);

        float bb[8], gm[8], bt[8];
        #pragma unroll
        for (int t = 0; t < 8; ++t) {
            const int cc = ch * 128 + t * 16 + col;
            bb[t] = b2_[cc]; gm[t] = g2[cc]; bt[t] = be2[cc];
        }
        #pragma unroll
        for (int r = 0; r < 4; ++r) {
            float s1 = 0.f, s2 = 0.f;
            #pragma unroll
            for (int t = 0; t < 8; ++t) {
                const float v = accc[t][r] + bb[t] + val[r][t];
                val[r][t] = v; s1 += v; s2 += v * v;
            }
            s1 += __shfl_xor(s1, 1); s1 += __shfl_xor(s1, 2);
            s1 += __shfl_xor(s1, 4); s1 += __shfl_xor(s1, 8);
            s2 += __shfl_xor(s2, 1); s2 += __shfl_xor(s2, 2);
            s2 += __shfl_xor(s2, 4); s2 += __shfl_xor(s2, 8);
            if (col == 0) { red[rt][ch][quad * 4 + r][0] = s1; red[rt][ch][quad * 4 + r][1] = s2; }
        }
        __syncthreads();
        #pragma unroll
        for (int r = 0; r < 4; ++r) {
            const int qr = quad * 4 + r;
            const float s1 = red[rt][0][qr][0] + red[rt][1][qr][0];
            const float s2 = red[rt][0][qr][1] + red[rt][1][qr][1];
            const float mu = s1 * (1.0f / 256.0f);
            const float rv = rsqrtf(s2 * (1.0f / 256.0f) - mu * mu + 1e-5f);
            const int row = row0 + trow + r;
            #pragma unroll
            for (int t = 0; t < 8; ++t) {
                const float o = (val[r][t] - mu) * rv * gm[t] + bt[t];
                if (QKV) trans[trow + r][ch * 128 + t * 16 + col] = (__bf16)o;
                if (!LASTX)
                    xout[(size_t)row * 256 + ch * 128 + t * 16 + col] = o;
                else if ((row & 1023) == 0)          // only n==0 rows needed for bn
                    xout[(size_t)row * 256 + ch * 128 + t * 16 + col] = o;
            }
        }
        __syncthreads();
    }

    if (QKV) {
        bf16x8 af3[8];
        #pragma unroll
        for (int kc = 0; kc < 8; ++kc)
            af3[kc] = *(const bf16x8*)(&trans[rowL][kc * 32 + quad * 8]);
        const int bq_ = row0 >> 10;                  // batch (uniform per block)
        const int n0q = (row0 & 1023) + trow;        // n of this lane's C-rows
        for (int cg = 0; cg < 3; ++cg) {
            f32x4 accq[8];
            gemm8<4>(af3, wq + (size_t)cg * 256 * 256, wlds, mrow, kcol, ch, col, quad, accq);
            if (cg == 2) {
                #pragma unroll
                for (int t = 0; t < 8; ++t) {
                    const int cc = ch * 128 + t * 16 + col;
                    const int h = cc >> 5, dh = cc & 31;
                    const float bbv = bq[512 + cc];
                    bf16x4 p;
                    #pragma unroll
                    for (int r = 0; r < 4; ++r) p[r] = (__bf16)(accq[t][r] + bbv);
                    *(bf16x4*)(vtb + ((((size_t)(bq_ * 8 + h)) * 32 + dh) << 10) + n0q) = p;
                }
            } else {
                const float qs = (cg == 0) ? 0.25505402616305625f : 1.0f;  // log2e/sqrt(32)
                __bf16* dst = (cg == 0) ? qb : kb;
                #pragma unroll
                for (int t = 0; t < 8; ++t) {
                    const int cc = ch * 128 + t * 16 + col;
                    const int h = cc >> 5, dh = cc & 31;
                    const float bbv = bq[cg * 256 + cc];
                    #pragma unroll
                    for (int r = 0; r < 4; ++r)
                        dst[((((size_t)(bq_ * 8 + h)) << 10) + n0q + r) * 32 + dh] =
                            (__bf16)((accq[t][r] + bbv) * qs);
                }
            }
        }
    }
}

// ---------------------------------------------------------------------------
// MFMA flash attention. Grid (64 bh-swizzled, 8 q-chunks); block 4 waves x 32 q.
// XCD j owns batch b=j (L2-resident K/V/Q/mask). K prefetch + double-buffered P.
// ---------------------------------------------------------------------------
__global__ __launch_bounds__(256)
void attn_mfma(const __bf16* __restrict__ Qb, const __bf16* __restrict__ Kb,
               const __bf16* __restrict__ Vt, const unsigned char* __restrict__ MP,
               __bf16* __restrict__ O)
{
    __shared__ __bf16 pbuf[2][4][2][16][72];
    const int tid = threadIdx.x;
    const int lane = tid & 63;
    const int wv = tid >> 6;
    const int col = lane & 15;
    const int quad = lane >> 4;
    const int xr = blockIdx.x;
    const int bh = ((xr & 7) << 3) | (xr >> 3);     // XCD = x%8 = batch b
    const int b = bh >> 3, h = bh & 7;
    const int qbase = blockIdx.y * 128 + wv * 32;
    const int hsel = (h < 2) ? 0 : 1;
    const bool masked = (h < 6);

    bf16x8 qf[2];
    #pragma unroll
    for (int j = 0; j < 2; ++j)
        qf[j] = *(const bf16x8*)(Qb + ((size_t)bh * Nn + qbase + j * 16 + col) * DHc + quad * 8);

    bf16x8 onesf;
    {
        const __bf16 one = (__bf16)1.0f, zero = (__bf16)0.0f;
        #pragma unroll
        for (int j = 0; j < 8; ++j) onesf[j] = (col == 0) ? one : zero;
    }

    f32x4 O0[2], O1[2], OL[2];
    #pragma unroll
    for (int j = 0; j < 2; ++j) {
        O0[j] = (f32x4){0.f, 0.f, 0.f, 0.f};
        O1[j] = (f32x4){0.f, 0.f, 0.f, 0.f};
        OL[j] = (f32x4){0.f, 0.f, 0.f, 0.f};
    }
    const f32x4 zf = {0.f, 0.f, 0.f, 0.f};
    const __bf16* kbase = Kb + (size_t)bh * Nn * DHc;

    bf16x8 kf[4];
    #pragma unroll
    for (int t = 0; t < 4; ++t)
        kf[t] = *(const bf16x8*)(kbase + (size_t)(t * 16 + col) * DHc + quad * 8);

    for (int c = 0; c < 16; ++c) {
        bf16x8 kn[4];
        if (c < 15)
            #pragma unroll
            for (int t = 0; t < 4; ++t)
                kn[t] = *(const bf16x8*)(kbase + (size_t)((c + 1) * 64 + t * 16 + col) * DHc + quad * 8);
        uchar4 mk[2];
        if (masked)
            #pragma unroll
            for (int j = 0; j < 2; ++j)
                mk[j] = *(const uchar4*)(MP + ((((size_t)b << 10) + qbase + j * 16 + col) << 8)
                                            + (c << 4) + (quad << 2));
        #pragma unroll
        for (int j = 0; j < 2; ++j) {
            f32x4 S[4];
            #pragma unroll
            for (int t = 0; t < 4; ++t)
                S[t] = __builtin_amdgcn_mfma_f32_16x16x32_bf16(kf[t], qf[j], zf, 0, 0, 0);
            if (masked) {
                const unsigned char mb[4] = {mk[j].x, mk[j].y, mk[j].z, mk[j].w};
                #pragma unroll
                for (int t = 0; t < 4; ++t)
                    #pragma unroll
                    for (int r = 0; r < 4; ++r)
                        if (!((mb[t] >> (2 * r + hsel)) & 1)) S[t][r] = -INFINITY;
            }
            #pragma unroll
            for (int t = 0; t < 4; ++t) {
                bf16x4 p4;
                #pragma unroll
                for (int r = 0; r < 4; ++r)
                    p4[r] = (__bf16)__builtin_amdgcn_exp2f(S[t][r]);
                *(bf16x4*)(&pbuf[c & 1][wv][j][col][t * 16 + quad * 4]) = p4;
            }
        }
        const __bf16* vp = Vt + (size_t)bh * DHc * Nn + c * 64 + quad * 8;
        #pragma unroll
        for (int kh = 0; kh < 2; ++kh) {
            const bf16x8 v0 = *(const bf16x8*)(vp + (size_t)col * Nn + kh * 32);
            const bf16x8 v1 = *(const bf16x8*)(vp + (size_t)(col + 16) * Nn + kh * 32);
            #pragma unroll
            for (int j = 0; j < 2; ++j) {
                const bf16x8 pf = *(const bf16x8*)(&pbuf[c & 1][wv][j][col][kh * 32 + quad * 8]);
                O0[j] = __builtin_amdgcn_mfma_f32_16x16x32_bf16(pf, v0, O0[j], 0, 0, 0);
                O1[j] = __builtin_amdgcn_mfma_f32_16x16x32_bf16(pf, v1, O1[j], 0, 0, 0);
                OL[j] = __builtin_amdgcn_mfma_f32_16x16x32_bf16(pf, onesf, OL[j], 0, 0, 0);
            }
        }
        if (c < 15)
            #pragma unroll
            for (int t = 0; t < 4; ++t) kf[t] = kn[t];
    }
    #pragma unroll
    for (int j = 0; j < 2; ++j)
        #pragma unroll
        for (int r = 0; r < 4; ++r) {
            const float Lr = __shfl(OL[j][r], lane & 48);
            const float inv = 1.0f / Lr;
            const int q = qbase + j * 16 + quad * 4 + r;
            __bf16* op = O + ((size_t)(b * 1024 + q)) * 256 + h * 32 + col;
            op[0]  = (__bf16)(O0[j][r] * inv);
            op[16] = (__bf16)(O1[j][r] * inv);
        }
}

// ---------------------------------------------------------------------------
// Final: y = x[n=0] (b=0..7), batch-norm over B, scale/shift.
// x layout (B,N,HID): row b*1024.
// ---------------------------------------------------------------------------
__global__ __launch_bounds__(256)
void final_bn(const float* __restrict__ x, const float* __restrict__ g,
              const float* __restrict__ bta, float* __restrict__ out)
{
    const int d = threadIdx.x;
    float y[8]; float mu = 0.0f;
    #pragma unroll
    for (int i = 0; i < 8; ++i) { y[i] = x[((size_t)i << 18) + d]; mu += y[i]; }
    mu *= 0.125f;
    float var = 0.0f;
    #pragma unroll
    for (int i = 0; i < 8; ++i) { const float dd = y[i] - mu; var += dd * dd; }
    var *= 0.125f;
    const float r = rsqrtf(var + 1e-5f);
    const float gg = g[d], bb = bta[d];
    #pragma unroll
    for (int i = 0; i < 8; ++i) out[i * 256 + d] = (y[i] - mu) * r * gg + bb;
}

extern "C" void kernel_launch(void* const* d_in, const int* in_sizes, int n_in,
                              void* d_out, int out_size, void* d_ws, size_t ws_size,
                              hipStream_t stream)
{
    const float* nodes   = (const float*)d_in[0];
    const int*   dist    = (const int*)  d_in[1];
    const float* W_in    = (const float*)d_in[2];
    const float* b_in    = (const float*)d_in[3];
    const float* ln_in_g = (const float*)d_in[4];
    const float* ln_in_b = (const float*)d_in[5];
    const float* Wqkv    = (const float*)d_in[6];
    const float* bqkv    = (const float*)d_in[7];
    const float* Wo      = (const float*)d_in[8];
    const float* bo      = (const float*)d_in[9];
    const float* ln1_g   = (const float*)d_in[10];
    const float* ln1_b   = (const float*)d_in[11];
    const float* W1      = (const float*)d_in[12];
    const float* b1      = (const float*)d_in[13];
    const float* W2      = (const float*)d_in[14];
    const float* b2      = (const float*)d_in[15];
    const float* ln2_g   = (const float*)d_in[16];
    const float* ln2_b   = (const float*)d_in[17];
    const float* bn_g    = (const float*)d_in[18];
    const float* bn_b    = (const float*)d_in[19];

    // workspace (byte offsets), 28.25 MB used
    char* ws = (char*)d_ws;
    float*  x   = (float*)(ws);                          // 8 MB fp32 residual (B,N,HID)
    unsigned char* mp = (unsigned char*)(ws + 8388608);  // 2 MB packed mask
    __bf16* wt  = (__bf16*)(ws + 10485760);              // 2.25 MB weights^T
    __bf16* qb  = (__bf16*)(ws + 12845056);              // 4 MB
    __bf16* kb  = (__bf16*)(ws + 17039360);              // 4 MB
    __bf16* vtb = (__bf16*)(ws + 21233664);              // 4 MB (V^T)
    __bf16* ob  = (__bf16*)(ws + 25427968);              // 4 MB attn out
    __bf16* xinb = ob;   // aliases ob (ob first written after fused1 consumed xinb)

    WCvtArgs wa;
    wa.src[0] = W_in;           wa.K[0] = 256; wa.M[0] = 256; wa.dstOff[0] = 0;
    wa.src[1] = Wqkv;           wa.K[1] = 256; wa.M[1] = 768; wa.dstOff[1] = 65536;
    wa.src[2] = Wqkv + 196608;  wa.K[2] = 256; wa.M[2] = 768; wa.dstOff[2] = 262144;
    wa.src[3] = Wo;             wa.K[3] = 256; wa.M[3] = 256; wa.dstOff[3] = 458752;
    wa.src[4] = Wo + 65536;     wa.K[4] = 256; wa.M[4] = 256; wa.dstOff[4] = 524288;
    wa.src[5] = W1;             wa.K[5] = 256; wa.M[5] = 512; wa.dstOff[5] = 589824;
    wa.src[6] = W1 + 131072;    wa.K[6] = 256; wa.M[6] = 512; wa.dstOff[6] = 720896;
    wa.src[7] = W2;             wa.K[7] = 512; wa.M[7] = 256; wa.dstOff[7] = 851968;
    wa.src[8] = W2 + 131072;    wa.K[8] = 512; wa.M[8] = 256; wa.dstOff[8] = 983040;
    for (int i = 0; i < 9; ++i) wa.tiles[i] = (wa.K[i] >> 5) * (wa.M[i] >> 5);

    prep_k<<<7232, 256, 0, stream>>>(wa, wt, dist, mp, nodes, xinb);

    // fused1: x = LN(xin @ W_in + b_in); QKV layer 0
    layer_k<false, false, true, false><<<256, 256, 0, stream>>>(
        xinb, nullptr, wt, b_in, ln_in_g, ln_in_b,
        nullptr, nullptr, nullptr, nullptr, nullptr, nullptr,
        wt + 65536, bqkv, x, qb, kb, vtb);

    attn_mfma<<<dim3(64, 8), 256, 0, stream>>>(qb, kb, vtb, mp, ob);

    // fused2: Wo0+LN1+FFN0+LN2 ; QKV layer 1
    layer_k<true, true, true, false><<<256, 256, 0, stream>>>(
        ob, x, wt + 458752, bo, ln1_g, ln1_b,
        wt + 589824, b1, wt + 851968, b2, ln2_g, ln2_b,
        wt + 262144, bqkv + 768, x, qb, kb, vtb);

    attn_mfma<<<dim3(64, 8), 256, 0, stream>>>(qb, kb, vtb, mp, ob);

    // fused3: Wo1+LN1+FFN1+LN2 (store only n==0 rows)
    layer_k<true, true, false, true><<<256, 256, 0, stream>>>(
        ob, x, wt + 524288, bo + 256, ln1_g + 256, ln1_b + 256,
        wt + 720896, b1 + 512, wt + 983040, b2 + 256, ln2_g + 256, ln2_b + 256,
        nullptr, nullptr, x, nullptr, nullptr, nullptr);

    final_bn<<<1, 256, 0, stream>>>(x, bn_g, bn_b, (float*)d_out);
}

// Round 8
// 252.695 us; speedup vs baseline: 1.4483x; 1.0410x over previous
//
#include <hip/hip_runtime.h>
#include <math.h>

// dims
constexpr int Nn = 1024, Bb = 8, HIDc = 256, Hh = 8, DHc = 32;

typedef __bf16 bf16x8 __attribute__((ext_vector_type(8)));
typedef __bf16 bf16x4 __attribute__((ext_vector_type(4)));
typedef float  f32x4  __attribute__((ext_vector_type(4)));

// ---------------------------------------------------------------------------
// prep_k: fused one-time preprocessing.
//   [0,1088):     weight convert+transpose Wt[m][k] = bf16(W[k][m])
//   [1088,3136):  mask pack  mp[b][n][c*16 + quad*4 + t], bit(2r+sel):
//                 sel0=(d==1), sel1=(d>=1), key = c*64 + t*16 + quad*4 + r
//   [3136,7232):  xinb[(b*1024+n)*256+k] = bf16(nodes[n][b][k] + PE(n,k))
// ---------------------------------------------------------------------------
struct WCvtArgs {
    const float* src[9];
    int K[9], M[9], dstOff[9], tiles[9];
};

__global__ __launch_bounds__(256)
void prep_k(WCvtArgs a, __bf16* __restrict__ Wt,
            const int* __restrict__ dist, unsigned char* __restrict__ mp,
            const float* __restrict__ nodes, __bf16* __restrict__ xinb)
{
    __shared__ float ts[32][33];
    const int tid = threadIdx.x;
    if (blockIdx.x < 1088) {
        int bid = blockIdx.x, i = 0;
        while (bid >= a.tiles[i]) { bid -= a.tiles[i]; ++i; }
        const int K = a.K[i], M = a.M[i];
        const int tilesM = M >> 5;
        const int m0 = (bid % tilesM) << 5, k0 = (bid / tilesM) << 5;
        const float* src = a.src[i];
        __bf16* dst = Wt + a.dstOff[i];
        const int tx = tid & 31, ty = tid >> 5;
        #pragma unroll
        for (int j = 0; j < 4; ++j)
            ts[ty + 8 * j][tx] = src[(size_t)(k0 + ty + 8 * j) * M + m0 + tx];
        __syncthreads();
        #pragma unroll
        for (int j = 0; j < 4; ++j)
            dst[(size_t)(m0 + ty + 8 * j) * K + k0 + tx] = (__bf16)ts[tx][ty + 8 * j];
    } else if (blockIdx.x < 3136) {
        const int idx = (blockIdx.x - 1088) * 256 + tid;   // 524288 items
        const int quad = idx & 3, c = (idx >> 2) & 15, q = (idx >> 6) & 1023, b = idx >> 16;
        const int* dp = dist + ((((size_t)b << 10) + q) << 10) + c * 64 + quad * 4;
        uchar4 out;
        unsigned char* po = &out.x;
        #pragma unroll
        for (int t = 0; t < 4; ++t) {
            const int4 v = *(const int4*)(dp + t * 16);
            unsigned int code = 0;
            const int dd[4] = {v.x, v.y, v.z, v.w};
            #pragma unroll
            for (int r = 0; r < 4; ++r)
                code |= ((dd[r] == 1 ? 1u : 0u) | (dd[r] >= 1 ? 2u : 0u)) << (2 * r);
            po[t] = (unsigned char)code;
        }
        *(uchar4*)(mp + ((((size_t)b << 10) + q) << 8) + (c << 4) + (quad << 2)) = out;
    } else {
        const int idx = (blockIdx.x - 3136) * 256 + tid;   // 1M items
        const int token = idx >> 7, k2 = (idx & 127) * 2;  // token = b*1024 + n
        const int b = token >> 10, n = token & 1023;
        const float e = (float)k2 * (1.0f / 256.0f);
        const float freq = exp2f(-13.287712379549449f * e);
        const float ang = (float)n * freq;
        const float2 nd = *(const float2*)(nodes + ((size_t)(n * 8 + b)) * 256 + k2);
        __bf16* p = xinb + (size_t)token * 256 + k2;
        p[0] = (__bf16)(nd.x + sinf(ang));
        p[1] = (__bf16)(nd.y + cosf(ang));
    }
}

// ---------------------------------------------------------------------------
// gemm8: one 256-col GEMM stage, double-buffered LDS weight staging.
// Block = 4 waves = 2 row-tiles x 2 col-halves. 1 barrier per 64-k chunk;
// W prefetched 2 chunks ahead. Entry barrier protects aliased smem (trans).
// ---------------------------------------------------------------------------
template<int NCH>
__device__ __forceinline__ void gemm8(const bf16x8* af, const __bf16* __restrict__ wsrc,
                                      __bf16 (*wlds)[256][72], int mrow, int kcol,
                                      int ch, int col, int quad, f32x4* acc)
{
    constexpr int K = NCH * 64;
    bf16x8 wreg[8];
    #pragma unroll
    for (int i = 0; i < 8; ++i)
        wreg[i] = *(const bf16x8*)(wsrc + (size_t)(i * 32 + mrow) * K + kcol);
    __syncthreads();   // prior readers of aliased smem done
    #pragma unroll
    for (int i = 0; i < 8; ++i)
        *(bf16x8*)&wlds[0][i * 32 + mrow][kcol] = wreg[i];
    if (NCH > 1) {
        #pragma unroll
        for (int i = 0; i < 8; ++i)
            wreg[i] = *(const bf16x8*)(wsrc + (size_t)(i * 32 + mrow) * K + 64 + kcol);
    }
    __syncthreads();
    #pragma unroll
    for (int t = 0; t < 8; ++t) acc[t] = (f32x4){0.f, 0.f, 0.f, 0.f};
    for (int ck = 0; ck < NCH; ++ck) {
        #pragma unroll
        for (int t = 0; t < 8; ++t)
            #pragma unroll
            for (int kc = 0; kc < 2; ++kc) {
                const bf16x8 bfr = *(const bf16x8*)(&wlds[ck & 1][ch * 128 + t * 16 + col][kc * 32 + quad * 8]);
                acc[t] = __builtin_amdgcn_mfma_f32_16x16x32_bf16(af[ck * 2 + kc], bfr, acc[t], 0, 0, 0);
            }
        if (ck + 1 < NCH) {
            // safe: buf[(ck+1)&1] last read in iter ck-1, sealed by its barrier
            #pragma unroll
            for (int i = 0; i < 8; ++i)
                *(bf16x8*)&wlds[(ck + 1) & 1][i * 32 + mrow][kcol] = wreg[i];
            if (ck + 2 < NCH) {
                #pragma unroll
                for (int i = 0; i < 8; ++i)
                    wreg[i] = *(const bf16x8*)(wsrc + (size_t)(i * 32 + mrow) * K + (ck + 2) * 64 + kcol);
            }
        }
        __syncthreads();
    }
}

// ---------------------------------------------------------------------------
// layer_k: fused transformer block slab (32 token-rows per block).
//   stage A: y = Ain @ w0 + b0 (+ xres if RESID) -> LN(g1,be1)
//   if FFN:  h1 = relu(xA @ w1 + b1);  y2 = h1 @ w2 + b2 + xA -> LN(g2,be2)
//   xout fp32: full (!XGATE), or only rows with n==0 (XGATE / N0ROWS)
//   if QKV:  q (scaled log2e/sqrt(DH), only if qfull or block has n<32) /
//            k -> (B,H,N,DH); v -> V^T (B,H,DH,N)
// N0ROWS: grid=1; local row i -> global row (i&7)*1024 (n=0 rows of each b).
// Token layout (B,N,HID): token = b*1024 + n.
// ---------------------------------------------------------------------------
template<bool RESID, bool FFN, bool QKV, bool N0ROWS, bool XGATE>
__global__ __launch_bounds__(256)
void layer_k(const __bf16* __restrict__ Ain, const float* __restrict__ xres,
             const __bf16* __restrict__ w0, const float* __restrict__ b0,
             const float* __restrict__ g1, const float* __restrict__ be1,
             const __bf16* __restrict__ w1, const float* __restrict__ b1_,
             const __bf16* __restrict__ w2, const float* __restrict__ b2_,
             const float* __restrict__ g2, const float* __restrict__ be2,
             const __bf16* __restrict__ wq, const float* __restrict__ bq, int qfull,
             float* __restrict__ xout,
             __bf16* __restrict__ qb, __bf16* __restrict__ kb, __bf16* __restrict__ vtb)
{
    __shared__ char smem[73728];                     // 2x wlds; trans aliases buf0
    __bf16 (*wlds)[256][72] = (__bf16 (*)[256][72])smem;
    __bf16 (*trans)[520] = (__bf16 (*)[520])smem;    // [32][520]
    __shared__ float red[2][2][16][2];

    const int tid = threadIdx.x;
    const int lane = tid & 63;
    const int wv = tid >> 6;
    const int rt = wv >> 1, ch = wv & 1;
    const int col = lane & 15, quad = lane >> 4;
    const int row0 = blockIdx.x * 32;
    const int rowL = rt * 16 + col;                  // local A-row for this lane
    const int mrow = tid >> 3, kcol = (tid & 7) * 8;
    const int trow = rt * 16 + quad * 4;             // local C-row base

    const int rowAg = N0ROWS ? ((rowL & 7) << 10) : (row0 + rowL);

    // ---- stage A ----
    bf16x8 afA[8];
    #pragma unroll
    for (int kc = 0; kc < 8; ++kc)
        afA[kc] = *(const bf16x8*)(Ain + (size_t)rowAg * 256 + kc * 32 + quad * 8);
    f32x4 acc[8];
    gemm8<4>(afA, w0, wlds, mrow, kcol, ch, col, quad, acc);

    float val[4][8];
    {
        float bb[8], gm[8], bt[8];
        #pragma unroll
        for (int t = 0; t < 8; ++t) {
            const int cc = ch * 128 + t * 16 + col;
            bb[t] = b0[cc]; gm[t] = g1[cc]; bt[t] = be1[cc];
        }
        #pragma unroll
        for (int r = 0; r < 4; ++r) {
            const int rg = N0ROWS ? (((trow + r) & 7) << 10) : (row0 + trow + r);
            float s1 = 0.f, s2 = 0.f;
            #pragma unroll
            for (int t = 0; t < 8; ++t) {
                float v = acc[t][r] + bb[t];
                if (RESID) v += xres[(size_t)rg * 256 + ch * 128 + t * 16 + col];
                val[r][t] = v; s1 += v; s2 += v * v;
            }
            s1 += __shfl_xor(s1, 1); s1 += __shfl_xor(s1, 2);
            s1 += __shfl_xor(s1, 4); s1 += __shfl_xor(s1, 8);
            s2 += __shfl_xor(s2, 1); s2 += __shfl_xor(s2, 2);
            s2 += __shfl_xor(s2, 4); s2 += __shfl_xor(s2, 8);
            if (col == 0) { red[rt][ch][quad * 4 + r][0] = s1; red[rt][ch][quad * 4 + r][1] = s2; }
        }
        __syncthreads();
        #pragma unroll
        for (int r = 0; r < 4; ++r) {
            const int qr = quad * 4 + r;
            const float s1 = red[rt][0][qr][0] + red[rt][1][qr][0];
            const float s2 = red[rt][0][qr][1] + red[rt][1][qr][1];
            const float mu = s1 * (1.0f / 256.0f);
            const float rv = rsqrtf(s2 * (1.0f / 256.0f) - mu * mu + 1e-5f);
            #pragma unroll
            for (int t = 0; t < 8; ++t) {
                const float o = (val[r][t] - mu) * rv * gm[t] + bt[t];
                val[r][t] = o;
                trans[trow + r][ch * 128 + t * 16 + col] = (__bf16)o;
                if (!FFN)   // fused1: this LN is the kernel's final LN
                    xout[(size_t)(row0 + trow + r) * 256 + ch * 128 + t * 16 + col] = o;
            }
        }
        __syncthreads();
    }

    if (FFN) {
        // ---- FFN: h1 = relu(xA @ W1 + b1), 2 m-halves of 256 ----
        bf16x8 af1[8];
        #pragma unroll
        for (int kc = 0; kc < 8; ++kc)
            af1[kc] = *(const bf16x8*)(&trans[rowL][kc * 32 + quad * 8]);
        bf16x4 h1p[2][8];
        #pragma unroll
        for (int mh = 0; mh < 2; ++mh) {
            f32x4 accb[8];
            gemm8<4>(af1, w1 + (size_t)mh * 256 * 256, wlds, mrow, kcol, ch, col, quad, accb);
            #pragma unroll
            for (int t = 0; t < 8; ++t) {
                const float bbv = b1_[mh * 256 + ch * 128 + t * 16 + col];
                #pragma unroll
                for (int r = 0; r < 4; ++r)
                    h1p[mh][t][r] = (__bf16)fmaxf(accb[t][r] + bbv, 0.f);
            }
        }
        __syncthreads();
        #pragma unroll
        for (int mh = 0; mh < 2; ++mh)
            #pragma unroll
            for (int t = 0; t < 8; ++t)
                #pragma unroll
                for (int r = 0; r < 4; ++r)
                    trans[trow + r][mh * 256 + ch * 128 + t * 16 + col] = h1p[mh][t][r];
        __syncthreads();

        // ---- y2 = h1 @ W2 + b2 + xA -> LN2 ----
        bf16x8 af2[16];
        #pragma unroll
        for (int kc = 0; kc < 16; ++kc)
            af2[kc] = *(const bf16x8*)(&trans[rowL][kc * 32 + quad * 8]);
        f32x4 accc[8];
        gemm8<8>(af2, w2, wlds, mrow, kcol, ch, col, quad, accc);

        float bb[8], gm[8], bt[8];
        #pragma unroll
        for (int t = 0; t < 8; ++t) {
            const int cc = ch * 128 + t * 16 + col;
            bb[t] = b2_[cc]; gm[t] = g2[cc]; bt[t] = be2[cc];
        }
        #pragma unroll
        for (int r = 0; r < 4; ++r) {
            float s1 = 0.f, s2 = 0.f;
            #pragma unroll
            for (int t = 0; t < 8; ++t) {
                const float v = accc[t][r] + bb[t] + val[r][t];
                val[r][t] = v; s1 += v; s2 += v * v;
            }
            s1 += __shfl_xor(s1, 1); s1 += __shfl_xor(s1, 2);
            s1 += __shfl_xor(s1, 4); s1 += __shfl_xor(s1, 8);
            s2 += __shfl_xor(s2, 1); s2 += __shfl_xor(s2, 2);
            s2 += __shfl_xor(s2, 4); s2 += __shfl_xor(s2, 8);
            if (col == 0) { red[rt][ch][quad * 4 + r][0] = s1; red[rt][ch][quad * 4 + r][1] = s2; }
        }
        __syncthreads();
        #pragma unroll
        for (int r = 0; r < 4; ++r) {
            const int qr = quad * 4 + r;
            const float s1 = red[rt][0][qr][0] + red[rt][1][qr][0];
            const float s2 = red[rt][0][qr][1] + red[rt][1][qr][1];
            const float mu = s1 * (1.0f / 256.0f);
            const float rv = rsqrtf(s2 * (1.0f / 256.0f) - mu * mu + 1e-5f);
            const int rl = trow + r;
            const int rg = N0ROWS ? ((rl & 7) << 10) : (row0 + rl);
            #pragma unroll
            for (int t = 0; t < 8; ++t) {
                const float o = (val[r][t] - mu) * rv * gm[t] + bt[t];
                if (QKV) trans[rl][ch * 128 + t * 16 + col] = (__bf16)o;
                bool wr;
                if (N0ROWS)      wr = (rl < 8);
                else if (XGATE)  wr = ((rg & 1023) == 0);
                else             wr = true;
                if (wr) xout[(size_t)rg * 256 + ch * 128 + t * 16 + col] = o;
            }
        }
        __syncthreads();
    }

    if (QKV) {
        bf16x8 af3[8];
        #pragma unroll
        for (int kc = 0; kc < 8; ++kc)
            af3[kc] = *(const bf16x8*)(&trans[rowL][kc * 32 + quad * 8]);
        const int bq_ = row0 >> 10;                  // batch (uniform per block)
        const int n0q = (row0 & 1023) + trow;        // n of this lane's C-rows
        const bool qneed = qfull || ((row0 & 1023) == 0);
        for (int cg = 0; cg < 3; ++cg) {
            if (cg == 0 && !qneed) continue;         // block-uniform skip
            f32x4 accq[8];
            gemm8<4>(af3, wq + (size_t)cg * 256 * 256, wlds, mrow, kcol, ch, col, quad, accq);
            if (cg == 2) {
                #pragma unroll
                for (int t = 0; t < 8; ++t) {
                    const int cc = ch * 128 + t * 16 + col;
                    const int h = cc >> 5, dh = cc & 31;
                    const float bbv = bq[512 + cc];
                    bf16x4 p;
                    #pragma unroll
                    for (int r = 0; r < 4; ++r) p[r] = (__bf16)(accq[t][r] + bbv);
                    *(bf16x4*)(vtb + ((((size_t)(bq_ * 8 + h)) * 32 + dh) << 10) + n0q) = p;
                }
            } else {
                const float qs = (cg == 0) ? 0.25505402616305625f : 1.0f;  // log2e/sqrt(32)
                __bf16* dst = (cg == 0) ? qb : kb;
                #pragma unroll
                for (int t = 0; t < 8; ++t) {
                    const int cc = ch * 128 + t * 16 + col;
                    const int h = cc >> 5, dh = cc & 31;
                    const float bbv = bq[cg * 256 + cc];
                    #pragma unroll
                    for (int r = 0; r < 4; ++r)
                        dst[((((size_t)(bq_ * 8 + h)) << 10) + n0q + r) * 32 + dh] =
                            (__bf16)((accq[t][r] + bbv) * qs);
                }
            }
        }
    }
}

// ---------------------------------------------------------------------------
// MFMA flash attention. Grid (64 bh-swizzled, NQC q-chunks); block 4 waves x 32 q.
// XCD j owns batch b=j (L2-resident K/V/Q/mask). K prefetch + double-buffered P.
// ---------------------------------------------------------------------------
__global__ __launch_bounds__(256)
void attn_mfma(const __bf16* __restrict__ Qb, const __bf16* __restrict__ Kb,
               const __bf16* __restrict__ Vt, const unsigned char* __restrict__ MP,
               __bf16* __restrict__ O)
{
    __shared__ __bf16 pbuf[2][4][2][16][72];
    const int tid = threadIdx.x;
    const int lane = tid & 63;
    const int wv = tid >> 6;
    const int col = lane & 15;
    const int quad = lane >> 4;
    const int xr = blockIdx.x;
    const int bh = ((xr & 7) << 3) | (xr >> 3);     // XCD = x%8 = batch b
    const int b = bh >> 3, h = bh & 7;
    const int qbase = blockIdx.y * 128 + wv * 32;
    const int hsel = (h < 2) ? 0 : 1;
    const bool masked = (h < 6);

    bf16x8 qf[2];
    #pragma unroll
    for (int j = 0; j < 2; ++j)
        qf[j] = *(const bf16x8*)(Qb + ((size_t)bh * Nn + qbase + j * 16 + col) * DHc + quad * 8);

    bf16x8 onesf;
    {
        const __bf16 one = (__bf16)1.0f, zero = (__bf16)0.0f;
        #pragma unroll
        for (int j = 0; j < 8; ++j) onesf[j] = (col == 0) ? one : zero;
    }

    f32x4 O0[2], O1[2], OL[2];
    #pragma unroll
    for (int j = 0; j < 2; ++j) {
        O0[j] = (f32x4){0.f, 0.f, 0.f, 0.f};
        O1[j] = (f32x4){0.f, 0.f, 0.f, 0.f};
        OL[j] = (f32x4){0.f, 0.f, 0.f, 0.f};
    }
    const f32x4 zf = {0.f, 0.f, 0.f, 0.f};
    const __bf16* kbase = Kb + (size_t)bh * Nn * DHc;

    bf16x8 kf[4];
    #pragma unroll
    for (int t = 0; t < 4; ++t)
        kf[t] = *(const bf16x8*)(kbase + (size_t)(t * 16 + col) * DHc + quad * 8);

    for (int c = 0; c < 16; ++c) {
        bf16x8 kn[4];
        if (c < 15)
            #pragma unroll
            for (int t = 0; t < 4; ++t)
                kn[t] = *(const bf16x8*)(kbase + (size_t)((c + 1) * 64 + t * 16 + col) * DHc + quad * 8);
        uchar4 mk[2];
        if (masked)
            #pragma unroll
            for (int j = 0; j < 2; ++j)
                mk[j] = *(const uchar4*)(MP + ((((size_t)b << 10) + qbase + j * 16 + col) << 8)
                                            + (c << 4) + (quad << 2));
        #pragma unroll
        for (int j = 0; j < 2; ++j) {
            f32x4 S[4];
            #pragma unroll
            for (int t = 0; t < 4; ++t)
                S[t] = __builtin_amdgcn_mfma_f32_16x16x32_bf16(kf[t], qf[j], zf, 0, 0, 0);
            if (masked) {
                const unsigned char mb[4] = {mk[j].x, mk[j].y, mk[j].z, mk[j].w};
                #pragma unroll
                for (int t = 0; t < 4; ++t)
                    #pragma unroll
                    for (int r = 0; r < 4; ++r)
                        if (!((mb[t] >> (2 * r + hsel)) & 1)) S[t][r] = -INFINITY;
            }
            #pragma unroll
            for (int t = 0; t < 4; ++t) {
                bf16x4 p4;
                #pragma unroll
                for (int r = 0; r < 4; ++r)
                    p4[r] = (__bf16)__builtin_amdgcn_exp2f(S[t][r]);
                *(bf16x4*)(&pbuf[c & 1][wv][j][col][t * 16 + quad * 4]) = p4;
            }
        }
        const __bf16* vp = Vt + (size_t)bh * DHc * Nn + c * 64 + quad * 8;
        #pragma unroll
        for (int kh = 0; kh < 2; ++kh) {
            const bf16x8 v0 = *(const bf16x8*)(vp + (size_t)col * Nn + kh * 32);
            const bf16x8 v1 = *(const bf16x8*)(vp + (size_t)(col + 16) * Nn + kh * 32);
            #pragma unroll
            for (int j = 0; j < 2; ++j) {
                const bf16x8 pf = *(const bf16x8*)(&pbuf[c & 1][wv][j][col][kh * 32 + quad * 8]);
                O0[j] = __builtin_amdgcn_mfma_f32_16x16x32_bf16(pf, v0, O0[j], 0, 0, 0);
                O1[j] = __builtin_amdgcn_mfma_f32_16x16x32_bf16(pf, v1, O1[j], 0, 0, 0);
                OL[j] = __builtin_amdgcn_mfma_f32_16x16x32_bf16(pf, onesf, OL[j], 0, 0, 0);
            }
        }
        if (c < 15)
            #pragma unroll
            for (int t = 0; t < 4; ++t) kf[t] = kn[t];
    }
    #pragma unroll
    for (int j = 0; j < 2; ++j)
        #pragma unroll
        for (int r = 0; r < 4; ++r) {
            const float Lr = __shfl(OL[j][r], lane & 48);
            const float inv = 1.0f / Lr;
            const int q = qbase + j * 16 + quad * 4 + r;
            __bf16* op = O + ((size_t)(b * 1024 + q)) * 256 + h * 32 + col;
            op[0]  = (__bf16)(O0[j][r] * inv);
            op[16] = (__bf16)(O1[j][r] * inv);
        }
}

// ---------------------------------------------------------------------------
// Final: y = x[n=0] (b=0..7), batch-norm over B, scale/shift.
// x layout (B,N,HID): row b*1024.
// ---------------------------------------------------------------------------
__global__ __launch_bounds__(256)
void final_bn(const float* __restrict__ x, const float* __restrict__ g,
              const float* __restrict__ bta, float* __restrict__ out)
{
    const int d = threadIdx.x;
    float y[8]; float mu = 0.0f;
    #pragma unroll
    for (int i = 0; i < 8; ++i) { y[i] = x[((size_t)i << 18) + d]; mu += y[i]; }
    mu *= 0.125f;
    float var = 0.0f;
    #pragma unroll
    for (int i = 0; i < 8; ++i) { const float dd = y[i] - mu; var += dd * dd; }
    var *= 0.125f;
    const float r = rsqrtf(var + 1e-5f);
    const float gg = g[d], bb = bta[d];
    #pragma unroll
    for (int i = 0; i < 8; ++i) out[i * 256 + d] = (y[i] - mu) * r * gg + bb;
}

extern "C" void kernel_launch(void* const* d_in, const int* in_sizes, int n_in,
                              void* d_out, int out_size, void* d_ws, size_t ws_size,
                              hipStream_t stream)
{
    const float* nodes   = (const float*)d_in[0];
    const int*   dist    = (const int*)  d_in[1];
    const float* W_in    = (const float*)d_in[2];
    const float* b_in    = (const float*)d_in[3];
    const float* ln_in_g = (const float*)d_in[4];
    const float* ln_in_b = (const float*)d_in[5];
    const float* Wqkv    = (const float*)d_in[6];
    const float* bqkv    = (const float*)d_in[7];
    const float* Wo      = (const float*)d_in[8];
    const float* bo      = (const float*)d_in[9];
    const float* ln1_g   = (const float*)d_in[10];
    const float* ln1_b   = (const float*)d_in[11];
    const float* W1      = (const float*)d_in[12];
    const float* b1      = (const float*)d_in[13];
    const float* W2      = (const float*)d_in[14];
    const float* b2      = (const float*)d_in[15];
    const float* ln2_g   = (const float*)d_in[16];
    const float* ln2_b   = (const float*)d_in[17];
    const float* bn_g    = (const float*)d_in[18];
    const float* bn_b    = (const float*)d_in[19];

    // workspace (byte offsets), 28.25 MB used
    char* ws = (char*)d_ws;
    float*  x   = (float*)(ws);                          // 8 MB fp32 residual (B,N,HID)
    unsigned char* mp = (unsigned char*)(ws + 8388608);  // 2 MB packed mask
    __bf16* wt  = (__bf16*)(ws + 10485760);              // 2.25 MB weights^T
    __bf16* qb  = (__bf16*)(ws + 12845056);              // 4 MB
    __bf16* kb  = (__bf16*)(ws + 17039360);              // 4 MB
    __bf16* vtb = (__bf16*)(ws + 21233664);              // 4 MB (V^T)
    __bf16* ob  = (__bf16*)(ws + 25427968);              // 4 MB attn out
    __bf16* xinb = ob;   // aliases ob (ob first written after fused1 consumed xinb)

    WCvtArgs wa;
    wa.src[0] = W_in;           wa.K[0] = 256; wa.M[0] = 256; wa.dstOff[0] = 0;
    wa.src[1] = Wqkv;           wa.K[1] = 256; wa.M[1] = 768; wa.dstOff[1] = 65536;
    wa.src[2] = Wqkv + 196608;  wa.K[2] = 256; wa.M[2] = 768; wa.dstOff[2] = 262144;
    wa.src[3] = Wo;             wa.K[3] = 256; wa.M[3] = 256; wa.dstOff[3] = 458752;
    wa.src[4] = Wo + 65536;     wa.K[4] = 256; wa.M[4] = 256; wa.dstOff[4] = 524288;
    wa.src[5] = W1;             wa.K[5] = 256; wa.M[5] = 512; wa.dstOff[5] = 589824;
    wa.src[6] = W1 + 131072;    wa.K[6] = 256; wa.M[6] = 512; wa.dstOff[6] = 720896;
    wa.src[7] = W2;             wa.K[7] = 512; wa.M[7] = 256; wa.dstOff[7] = 851968;
    wa.src[8] = W2 + 131072;    wa.K[8] = 512; wa.M[8] = 256; wa.dstOff[8] = 983040;
    for (int i = 0; i < 9; ++i) wa.tiles[i] = (wa.K[i] >> 5) * (wa.M[i] >> 5);

    prep_k<<<7232, 256, 0, stream>>>(wa, wt, dist, mp, nodes, xinb);

    // fused1: x = LN(xin @ W_in + b_in); QKV layer 0 (full q)
    layer_k<false, false, true, false, false><<<256, 256, 0, stream>>>(
        xinb, nullptr, wt, b_in, ln_in_g, ln_in_b,
        nullptr, nullptr, nullptr, nullptr, nullptr, nullptr,
        wt + 65536, bqkv, 1, x, qb, kb, vtb);

    attn_mfma<<<dim3(64, 8), 256, 0, stream>>>(qb, kb, vtb, mp, ob);

    // fused2: Wo0+LN1+FFN0+LN2 (x stored only n==0); QKV layer 1 (q only n<32)
    layer_k<true, true, true, false, true><<<256, 256, 0, stream>>>(
        ob, x, wt + 458752, bo, ln1_g, ln1_b,
        wt + 589824, b1, wt + 851968, b2, ln2_g, ln2_b,
        wt + 262144, bqkv + 768, 0, x, qb, kb, vtb);

    // attn layer 1: only q in [0,128) needed (output consumed only at n==0)
    attn_mfma<<<dim3(64, 1), 256, 0, stream>>>(qb, kb, vtb, mp, ob);

    // fused3: Wo1+LN1+FFN1+LN2 on the 8 n==0 rows only (1 block)
    layer_k<true, true, false, true, true><<<1, 256, 0, stream>>>(
        ob, x, wt + 524288, bo + 256, ln1_g + 256, ln1_b + 256,
        wt + 720896, b1 + 512, wt + 983040, b2 + 256, ln2_g + 256, ln2_b + 256,
        nullptr, nullptr, 0, x, nullptr, nullptr, nullptr);

    final_bn<<<1, 256, 0, stream>>>(x, bn_g, bn_b, (float*)d_out);
}